// Round 9
// baseline (724.511 us; speedup 1.0000x reference)
//
#include <hip/hip_runtime.h>
#include <hip/hip_bf16.h>
#include <cstddef>
#include <cstdint>

typedef __attribute__((ext_vector_type(8))) short short8;
typedef __attribute__((ext_vector_type(4))) short short4v;
typedef __attribute__((ext_vector_type(4))) float floatx4;
typedef __hip_bfloat16 bf16;

#define HEADS 8
#define TOK   65536
#define OUTC  256

__device__ inline float b2f(short s) {
    union { unsigned u; float f; } x;
    x.u = ((unsigned)(unsigned short)s) << 16;
    return x.f;
}

// 16x16x16 bf16 MFMA. Builtin if present, else raw asm.
__device__ inline floatx4 mfma16(short4v a, short4v b, floatx4 c) {
#if __has_builtin(__builtin_amdgcn_mfma_f32_16x16x16bf16_1k)
    return __builtin_amdgcn_mfma_f32_16x16x16bf16_1k(a, b, c, 0, 0, 0);
#else
    floatx4 d;
    asm volatile("v_mfma_f32_16x16x16_bf16 %0, %1, %2, %3\n\ts_nop 7"
                 : "=v"(d) : "v"(a), "v"(b), "v"(c));
    return d;
#endif
}

// ---------------------------------------------------------------------------
// Transpose input (B,C,32,32,32) -> token-major xbuf[(b*32768+sp)*128 + c]
// + per-token LN stats (mu, rstd) for the layer-0 fused-LN QKV GEMM.
// ---------------------------------------------------------------------------
__global__ __launch_bounds__(256) void transpose_in_kernel(
    const float* __restrict__ x, float* __restrict__ out, float* __restrict__ tstats)
{
    __shared__ float tile[128 * 65];
    int chunk = blockIdx.x;
    int tid = threadIdx.x;
    int b = chunk >> 9;
    int sp0 = (chunk & 511) * 64;
    #pragma unroll
    for (int l = 0; l < 32; ++l) {
        int idx = l * 256 + tid;
        int c = idx >> 6;
        int s = idx & 63;
        tile[c * 65 + s] = x[(((size_t)(b * 128 + c)) << 15) + sp0 + s];
    }
    __syncthreads();
    #pragma unroll
    for (int l = 0; l < 32; ++l) {
        int idx = l * 256 + tid;
        int s = idx >> 7;
        int c = idx & 127;
        out[((size_t)((b << 15) + sp0 + s)) * 128 + c] = tile[c * 65 + s];
    }
    // per-token LN stats: 4 threads per token, 32 channels each
    int s = tid >> 2, q = tid & 3;
    float sm = 0.f, sq = 0.f;
    #pragma unroll
    for (int cc = 0; cc < 32; ++cc) {
        float v = tile[(q * 32 + cc) * 65 + s];
        sm += v; sq += v * v;
    }
    sm += __shfl_xor(sm, 1); sq += __shfl_xor(sq, 1);
    sm += __shfl_xor(sm, 2); sq += __shfl_xor(sq, 2);
    if (q == 0) {
        float mu = sm * (1.0f / 128.0f);
        float var = sq * (1.0f / 128.0f) - mu * mu;
        size_t tok = (size_t)(b << 15) + sp0 + s;
        tstats[tok * 2]     = mu;
        tstats[tok * 2 + 1] = rsqrtf(var + 1e-5f);
    }
}

// ---------------------------------------------------------------------------
// Prep: weight fp32->bf16 conversions + dw-weight transpose + stats zero.
// qkv weights are LN1-gamma-folded. proj weights are packed into MFMA
// B-fragment order for the fused proj+MLP kernel:
//   idx bits wv(2)|ks(2)|nt(1)|lane(6)|j(3) ->
//   proj_w[n = wv*32+nt*16+(lane&15)][k = ks*32+(lane>>4)*8+j]
// ---------------------------------------------------------------------------
__global__ __launch_bounds__(256) void prep_kernel(
    const float* __restrict__ qkv_w, const float* __restrict__ proj_w,
    const float* __restrict__ fc1_w, const float* __restrict__ fc2_w,
    const float* __restrict__ pw_w, const float* __restrict__ dw_w,
    const float* __restrict__ norm1_g,
    bf16* __restrict__ wbf, float* __restrict__ dwt, float* __restrict__ stats)
{
    int i = blockIdx.x * 256 + threadIdx.x;
    float v;
    if (i < 196608) {
        int layer = i / 49152, k = i & 127;
        v = qkv_w[i] * norm1_g[layer * 128 + k];
    }
    else if (i < 262144) {
        int jd = i - 196608;
        int layer = jd >> 14, idx = jd & 16383;
        int j = idx & 7, lane = (idx >> 3) & 63;
        int nt = (idx >> 9) & 1, ks = (idx >> 10) & 3, wvv = (idx >> 12) & 3;
        int row = wvv * 32 + nt * 16 + (lane & 15);
        int col = ks * 32 + (lane >> 4) * 8 + j;
        v = proj_w[layer * 16384 + row * 128 + col];
    }
    else if (i < 524288)  v = fc1_w[i - 262144];
    else if (i < 786432)  v = fc2_w[i - 524288];
    else                  v = pw_w[i - 786432];
    wbf[i] = __float2bfloat16(v);
    if (i < 3456) {
        int c = i / 27, k = i % 27;
        dwt[k * 128 + c] = dw_w[i];
    }
    if (i < 512) stats[i] = 0.f;
}

// ---------------------------------------------------------------------------
// Fold LN betas into biases:
//  fb[0..1536)  : qkvb[l][n]  = qkv_b + sum_k qkv_w[l][n][k]*norm1_b[l][k]
//  fb[1536..3584): b1f[l][n]  = fc1_b + sum_k fc1_w[l][n][k]*norm2_b[l][k]
// ---------------------------------------------------------------------------
__global__ __launch_bounds__(256) void foldbias_kernel(
    const float* __restrict__ qkv_w, const float* __restrict__ qkv_b,
    const float* __restrict__ norm1_b,
    const float* __restrict__ fc1_w, const float* __restrict__ fc1_b,
    const float* __restrict__ norm2_b, float* __restrict__ fb)
{
    int t = blockIdx.x * 256 + threadIdx.x;
    if (t < 1536) {
        int l = t / 384, n = t % 384;
        const float* wr = qkv_w + (size_t)l * 49152 + n * 128;
        const float* br = norm1_b + l * 128;
        float s = qkv_b[t];
        #pragma unroll 4
        for (int k = 0; k < 128; ++k) s += wr[k] * br[k];
        fb[t] = s;
    } else if (t < 3584) {
        int u = t - 1536;
        int l = u >> 9, n = u & 511;
        const float* wr = fc1_w + (size_t)l * 65536 + n * 128;
        const float* br = norm2_b + l * 128;
        float s = fc1_b[l * 512 + n];
        #pragma unroll 4
        for (int k = 0; k < 128; ++k) s += wr[k] * br[k];
        fb[t] = s;
    }
}

// ---------------------------------------------------------------------------
// Pack fc1/fc2 weights into MFMA-fragment order for the 4-chunk MLP.
// pw1 is LN2-gamma-folded (gamma indexes the k dimension = col).
// pw1 flat idx bits: cc(2)|wv(2)|kk(2)|nt(1)|lane(6)|j(3) ->
//   fc1_w[row = cc*128 + wv*32 + nt*16 + (lane&15)][col = kk*32 + (lane>>4)*8 + j]
// pw2 flat idx bits: wv(2)|cc(2)|ks(2)|nt(1)|lane(6)|j(3) ->
//   fc2_w[row = wv*32 + nt*16 + (lane&15)][col = cc*128 + ks*32 + (lane>>4)*8 + j]
// ---------------------------------------------------------------------------
__global__ __launch_bounds__(256) void pack_kernel(
    const float* __restrict__ fc1_w, const float* __restrict__ fc2_w,
    const float* __restrict__ norm2_g,
    bf16* __restrict__ pw1, bf16* __restrict__ pw2)
{
    int t = blockIdx.x * 256 + threadIdx.x;
    int i = t >> 17;
    int rem = t & 131071;
    int type = rem >> 16;
    int idx = rem & 65535;
    int j = idx & 7, lane = (idx >> 3) & 63;
    int ln15 = lane & 15, quad = lane >> 4;
    if (type == 0) {
        int nt = (idx >> 9) & 1, kk = (idx >> 10) & 3, wv = (idx >> 12) & 3, cc = (idx >> 14) & 3;
        int row = cc * 128 + wv * 32 + nt * 16 + ln15;
        int col = kk * 32 + quad * 8 + j;
        pw1[i * 65536 + idx] = __float2bfloat16(
            fc1_w[(size_t)i * 65536 + row * 128 + col] * norm2_g[i * 128 + col]);
    } else {
        int nt = (idx >> 9) & 1, ks = (idx >> 10) & 3, cc = (idx >> 12) & 3, wv = (idx >> 14) & 3;
        int row = wv * 32 + nt * 16 + ln15;
        int col = cc * 128 + ks * 32 + quad * 8 + j;
        pw2[i * 65536 + idx] = __float2bfloat16(fc2_w[(size_t)i * 65536 + row * 512 + col]);
    }
}

// ---------------------------------------------------------------------------
// Expand relative-position bias + shift mask into rpe[wtype][head][64][64] f32.
// ---------------------------------------------------------------------------
__global__ __launch_bounds__(256) void rpe_expand_kernel(
    const float* __restrict__ rpb, float* __restrict__ rpe, int layer)
{
    int t = blockIdx.x * 256 + threadIdx.x;
    int j = t & 63, i = (t >> 6) & 63, head = (t >> 12) & 7, wt = t >> 15;
    int ih = i >> 4, iw = (i >> 2) & 3, it = i & 3;
    int jh = j >> 4, jw = (j >> 2) & 3, jt = j & 3;
    int ridx = ((ih - jh + 3) * 7 + (iw - jw + 3)) * 7 + (it - jt + 3);
    float v = rpb[layer * 2744 + ridx * 8 + head];
    if (wt) {
        bool ok = true;
        if (wt & 4) ok = ok && ((ih >= 2) == (jh >= 2));
        if (wt & 2) ok = ok && ((iw >= 2) == (jw >= 2));
        if (wt & 1) ok = ok && ((it >= 2) == (jt >= 2));
        if (!ok) v -= 100.f;
    }
    rpe[t] = v;
}

// ---------------------------------------------------------------------------
// bf16 MFMA GEMM with coalesced LDS-staged epilogues.
// mode 0 (QKV): A-staging gathers fp32 rows from xbuf (Cf) with the shift-
// window token map and applies bf16((x-mu)*rstd) — gamma/beta folded into
// weights/bias. q columns (nBase==0) pre-scaled 0.25 in epilogue.
// mode 4/5: pointwise-conv stats / BN+ReLU epilogues (connectBlock).
// ---------------------------------------------------------------------------
__global__ __launch_bounds__(256) void gemm_bf16_kernel(
    const bf16* __restrict__ A, const bf16* __restrict__ Bw,
    const float* __restrict__ bias, bf16* __restrict__ Cb, float* __restrict__ Cf,
    float* __restrict__ aux, const float* __restrict__ p1, const float* __restrict__ p2,
    int M, int N, int K, int mode, int shift)
{
    __shared__ __align__(16) char smem[34816];
    __shared__ float cs[128];
    __shared__ float cq[128];
    short* As = (short*)smem;
    short* Bs = (short*)(smem + 8192);
    int tid = threadIdx.x;
    int lane = tid & 63, wv = tid >> 6;
    int wm = wv >> 1, wn = wv & 1;
    int ln15 = lane & 15, quad = lane >> 4;
    int q8 = quad * 8;
    int nBase = blockIdx.x * 128;
    int mBase = blockIdx.y * 128;
    floatx4 acc[4][4] = {};

    if (mode == 4 && tid < 128) { cs[tid] = 0.f; cq[tid] = 0.f; }

    int srow = tid >> 2, scb = tid & 3;

    int toks[2]; float tmu[2], trs[2];
    if (mode == 0) {
        #pragma unroll
        for (int i = 0; i < 2; ++i) {
            int m = mBase + srow + i * 64;
            int n = m & 63, w = (m >> 6) & 511, b = m >> 15;
            int ih = n >> 4, iw = (n >> 2) & 3, it = n & 3;
            int wh = w >> 6, ww = (w >> 3) & 7, wt = w & 7;
            int h  = (wh * 4 + ih + shift) & 31;
            int w2 = (ww * 4 + iw + shift) & 31;
            int t  = (wt * 4 + it + shift) & 31;
            toks[i] = (b << 15) + ((h * 32 + w2) * 32 + t);
            tmu[i] = aux[(size_t)toks[i] * 2];
            trs[i] = aux[(size_t)toks[i] * 2 + 1];
        }
    }

    for (int k0 = 0; k0 < K; k0 += 32) {
        if (mode == 0) {
            int cb = k0 + scb * 8;
            #pragma unroll
            for (int i = 0; i < 2; ++i) {
                const float* xr = Cf + (size_t)toks[i] * 128 + cb;
                float4 a0 = *(const float4*)xr;
                float4 a1 = *(const float4*)(xr + 4);
                float mu = tmu[i], rs = trs[i];
                __align__(16) bf16 pk[8];
                pk[0] = __float2bfloat16((a0.x - mu) * rs);
                pk[1] = __float2bfloat16((a0.y - mu) * rs);
                pk[2] = __float2bfloat16((a0.z - mu) * rs);
                pk[3] = __float2bfloat16((a0.w - mu) * rs);
                pk[4] = __float2bfloat16((a1.x - mu) * rs);
                pk[5] = __float2bfloat16((a1.y - mu) * rs);
                pk[6] = __float2bfloat16((a1.z - mu) * rs);
                pk[7] = __float2bfloat16((a1.w - mu) * rs);
                ((uint4*)As)[i * 256 + tid] = *(const uint4*)pk;
                ((uint4*)Bs)[i * 256 + tid] =
                    *(const uint4*)(Bw + (size_t)(nBase + srow + i * 64) * K + cb);
            }
        } else {
            #pragma unroll
            for (int i = 0; i < 2; ++i) {
                int row = srow + i * 64;
                ((uint4*)As)[i * 256 + tid] =
                    *(const uint4*)(A + (size_t)(mBase + row) * K + k0 + scb * 8);
                ((uint4*)Bs)[i * 256 + tid] =
                    *(const uint4*)(Bw + (size_t)(nBase + row) * K + k0 + scb * 8);
            }
        }
        __syncthreads();
        short8 af[4], bfr[4];
        #pragma unroll
        for (int mt = 0; mt < 4; ++mt)
            af[mt] = *(const short8*)&As[(wm * 64 + mt * 16 + ln15) * 32 + q8];
        #pragma unroll
        for (int nt = 0; nt < 4; ++nt)
            bfr[nt] = *(const short8*)&Bs[(wn * 64 + nt * 16 + ln15) * 32 + q8];
        #pragma unroll
        for (int mt = 0; mt < 4; ++mt)
            #pragma unroll
            for (int nt = 0; nt < 4; ++nt)
                acc[mt][nt] = __builtin_amdgcn_mfma_f32_16x16x32_bf16(
                    af[mt], bfr[nt], acc[mt][nt], 0, 0, 0);
        __syncthreads();
    }

    if (mode == 4) {
        #pragma unroll
        for (int nt = 0; nt < 4; ++nt) {
            int nl = wn * 64 + nt * 16 + ln15;
            float bs = bias[nBase + nl];
            float s = 0.f, sq = 0.f;
            #pragma unroll
            for (int mt = 0; mt < 4; ++mt)
                #pragma unroll
                for (int r = 0; r < 4; ++r) {
                    float v = acc[mt][nt][r] + bs;
                    s += v; sq += v * v;
                }
            atomicAdd(&cs[nl], s);
            atomicAdd(&cq[nl], sq);
        }
        __syncthreads();
        if (tid < 128) {
            atomicAdd(&aux[nBase + tid], cs[tid]);
            atomicAdd(&aux[256 + nBase + tid], cq[tid]);
        }
        return;
    }

    if (mode == 0) {
        bf16* estage = (bf16*)smem;          // [128][136]
        float qsc = (nBase == 0) ? 0.25f : 1.0f;
        #pragma unroll
        for (int mt = 0; mt < 4; ++mt)
            #pragma unroll
            for (int nt = 0; nt < 4; ++nt)
                #pragma unroll
                for (int r = 0; r < 4; ++r) {
                    int row = wm * 64 + mt * 16 + quad * 4 + r;
                    int col = wn * 64 + nt * 16 + ln15;
                    estage[row * 136 + col] =
                        __float2bfloat16((acc[mt][nt][r] + bias[nBase + col]) * qsc);
                }
        __syncthreads();
        int row = tid >> 1, hf = tid & 1;
        #pragma unroll
        for (int j = 0; j < 4; ++j) {
            int col = hf * 64 + j * 16;
            *(uint4*)(Cb + (size_t)(mBase + row) * N + nBase + col) =
                *(const uint4*)&estage[row * 136 + col];
            *(uint4*)(Cb + (size_t)(mBase + row) * N + nBase + col + 8) =
                *(const uint4*)&estage[row * 136 + col + 8];
        }
        return;
    }

    // mode 5: BN + ReLU + transposed store
    {
        float* fstage = (float*)smem;        // [64 nn][132 sp]
        int b = mBase >> 15, sp0 = mBase & 32767;
        #pragma unroll
        for (int hf = 0; hf < 2; ++hf) {
            if (wn == hf) {
                #pragma unroll
                for (int nt = 0; nt < 4; ++nt) {
                    int ncol = nt * 16 + ln15;
                    int nn = nBase + hf * 64 + ncol;
                    float mean = aux[nn] * (1.0f / 65536.0f);
                    float var  = aux[256 + nn] * (1.0f / 65536.0f) - mean * mean;
                    float sc = rsqrtf(var + 1e-5f) * p1[nn];
                    float off = p2[nn] + bias[nn] * sc - mean * sc;
                    #pragma unroll
                    for (int mt = 0; mt < 4; ++mt)
                        #pragma unroll
                        for (int r = 0; r < 4; ++r) {
                            int ml = wm * 64 + mt * 16 + quad * 4 + r;
                            float y = acc[mt][nt][r] * sc + off;
                            fstage[ncol * 132 + ml] = fmaxf(y, 0.f);
                        }
                }
            }
            __syncthreads();
            int nl = tid >> 2, part = tid & 3;
            int nn = nBase + hf * 64 + nl;
            float* dst = Cf + (((size_t)(b * 256 + nn)) << 15) + sp0 + part * 32;
            #pragma unroll
            for (int j = 0; j < 8; ++j)
                *(float4*)(dst + j * 4) = *(const float4*)&fstage[nl * 132 + part * 32 + j * 4];
            __syncthreads();
        }
    }
}

// ---------------------------------------------------------------------------
// Fused proj + residual + LN2 + MLP (v7.1). Each block = 64 natural-order
// tokens. x_mid = x + proj kept in REGISTERS. __launch_bounds__(256,3):
// the (256,4) variant capped the allocator at 128 VGPR and it spilled the
// 32-reg xm array to scratch (observed: VGPR=64, +53 MB/dispatch scratch
// writes, 154 us first-touch dispatch). 3 blocks/CU -> 170 VGPR cap,
// spill-free; LDS 3x34 KB = 104 KB/CU fits.
// ---------------------------------------------------------------------------
__global__ __launch_bounds__(256, 3) void mlp_kernel(
    float* __restrict__ xbuf, const bf16* __restrict__ attnbuf,
    const bf16* __restrict__ ppw, const float* __restrict__ pb,
    const bf16* __restrict__ pw1, const float* __restrict__ b1,
    const bf16* __restrict__ pw2, const float* __restrict__ b2,
    bf16* __restrict__ xout16, float* __restrict__ tstats, int shift)
{
    __shared__ __align__(16) bf16 smem[64 * 136 * 2];   // 34 KB
    bf16* aln  = smem;              // [64][136] atile / LN2'd x_mid
    bf16* hidc = smem + 64 * 136;   // [64][136] per-chunk hidden
    float* ostage = (float*)smem;   // [64][132] f32, full-smem alias
    int tid = threadIdx.x;
    int lane = tid & 63, wv = tid >> 6;
    int ln15 = lane & 15, quad = lane >> 4;
    int q8 = quad * 8;
    int blk = blockIdx.x;
    size_t tok0 = (size_t)blk * 64;
    int b = blk >> 9, h = (blk >> 4) & 31, wpair = blk & 15;

    // 1. gather attnbuf (window order) -> atile rows in natural-local order
    #pragma unroll
    for (int l = 0; l < 4; ++l) {
        int q = l * 256 + tid;
        int row = q >> 4, c16 = q & 15;
        int w2 = wpair * 2 + (row >> 5), t = row & 31;
        int hs = (h - shift) & 31, ws = (w2 - shift) & 31, ts = (t - shift) & 31;
        int wr = (b << 15) + (((hs >> 2) * 64 + ((ws >> 2) << 3) + (ts >> 2)) << 6)
               + ((hs & 3) * 16 + ((ws & 3) << 2) + (ts & 3));
        *(uint4*)&aln[row * 136 + c16 * 8] =
            *(const uint4*)((const short*)attnbuf + (size_t)wr * 128 + c16 * 8);
    }
    __syncthreads();

    // 2. proj: out[64][128]; wave wv -> cols wv*32..+31, K=128
    floatx4 accp[4][2] = {};
    #pragma unroll
    for (int ks = 0; ks < 4; ++ks) {
        short8 af[4], bfr[2];
        #pragma unroll
        for (int mt = 0; mt < 4; ++mt)
            af[mt] = *(const short8*)&aln[(mt * 16 + ln15) * 136 + ks * 32 + q8];
        #pragma unroll
        for (int nt = 0; nt < 2; ++nt)
            bfr[nt] = *(const short8*)(ppw + wv * 4096 + ks * 1024 + nt * 512 + lane * 8);
        #pragma unroll
        for (int mt = 0; mt < 4; ++mt)
            #pragma unroll
            for (int nt = 0; nt < 2; ++nt)
                accp[mt][nt] = __builtin_amdgcn_mfma_f32_16x16x32_bf16(
                    af[mt], bfr[nt], accp[mt][nt], 0, 0, 0);
    }
    __syncthreads();   // atile dead -> ostage (full smem)

    #pragma unroll
    for (int mt = 0; mt < 4; ++mt)
        #pragma unroll
        for (int nt = 0; nt < 2; ++nt)
            #pragma unroll
            for (int r = 0; r < 4; ++r) {
                int m = mt * 16 + quad * 4 + r;
                int n = wv * 32 + nt * 16 + ln15;
                ostage[m * 132 + n] = accp[mt][nt][r] + pb[n];
            }
    __syncthreads();

    // 3. x_mid = xbuf + proj, kept in regs (32 VGPR)
    float4 xm[8];
    #pragma unroll
    for (int jj = 0; jj < 8; ++jj) {
        int idx = (jj * 256 + tid) * 4;
        int t = idx >> 7, c = idx & 127;
        float4 v = *(const float4*)(xbuf + tok0 * 128 + idx);
        float4 o = *(const float4*)&ostage[t * 132 + c];
        v.x += o.x; v.y += o.y; v.z += o.z; v.w += o.w;
        xm[jj] = v;
    }
    __syncthreads();   // all ostage reads done -> aln reusable

    // 4. LN2 from regs (gamma/beta folded into pw1/b1) -> aln bf16
    #pragma unroll
    for (int jj = 0; jj < 8; ++jj) {
        int idx = (jj * 256 + tid) * 4;
        int t = idx >> 7, c = idx & 127;
        float4 v = xm[jj];
        float ps = v.x + v.y + v.z + v.w;
        float pq = v.x * v.x + v.y * v.y + v.z * v.z + v.w * v.w;
        #pragma unroll
        for (int o2 = 16; o2 > 0; o2 >>= 1) {
            ps += __shfl_xor(ps, o2); pq += __shfl_xor(pq, o2);
        }
        float mu = ps * (1.0f / 128.0f);
        float var = pq * (1.0f / 128.0f) - mu * mu;
        float rs = rsqrtf(var + 1e-5f);
        __align__(8) bf16 hh[4];
        hh[0] = __float2bfloat16((v.x - mu) * rs);
        hh[1] = __float2bfloat16((v.y - mu) * rs);
        hh[2] = __float2bfloat16((v.z - mu) * rs);
        hh[3] = __float2bfloat16((v.w - mu) * rs);
        *(uint2*)&aln[t * 136 + c] = *(const uint2*)hh;
    }
    __syncthreads();

    // 5. 4-chunk MLP (R5-proven)
    floatx4 acc2[4][2] = {};
    #pragma unroll
    for (int cc = 0; cc < 4; ++cc) {
        floatx4 acc[4][2] = {};
        const bf16* p1w = pw1 + (size_t)(cc * 4 + wv) * 4096;
        #pragma unroll
        for (int kk = 0; kk < 4; ++kk) {
            short8 af[4], bfr[2];
            #pragma unroll
            for (int mt = 0; mt < 4; ++mt)
                af[mt] = *(const short8*)&aln[(mt * 16 + ln15) * 136 + kk * 32 + q8];
            #pragma unroll
            for (int nt = 0; nt < 2; ++nt)
                bfr[nt] = *(const short8*)(p1w + kk * 1024 + nt * 512 + lane * 8);
            #pragma unroll
            for (int mt = 0; mt < 4; ++mt)
                #pragma unroll
                for (int nt = 0; nt < 2; ++nt)
                    acc[mt][nt] = __builtin_amdgcn_mfma_f32_16x16x32_bf16(
                        af[mt], bfr[nt], acc[mt][nt], 0, 0, 0);
        }
        if (cc) __syncthreads();
        #pragma unroll
        for (int mt = 0; mt < 4; ++mt)
            #pragma unroll
            for (int nt = 0; nt < 2; ++nt)
                #pragma unroll
                for (int r = 0; r < 4; ++r) {
                    int m = mt * 16 + quad * 4 + r;
                    int ncl = wv * 32 + nt * 16 + ln15;
                    float v = acc[mt][nt][r] + b1[cc * 128 + ncl];
                    float u = v * (0.7978845608f + 0.0356774081f * v * v);
                    v = v * __builtin_amdgcn_rcpf(1.f + __expf(-2.f * u));
                    hidc[m * 136 + ncl] = __float2bfloat16(v);
                }
        __syncthreads();
        const bf16* p2w = pw2 + (size_t)(wv * 4 + cc) * 4096;
        #pragma unroll
        for (int ks = 0; ks < 4; ++ks) {
            short8 af[4], bfr[2];
            #pragma unroll
            for (int mt = 0; mt < 4; ++mt)
                af[mt] = *(const short8*)&hidc[(mt * 16 + ln15) * 136 + ks * 32 + q8];
            #pragma unroll
            for (int nt = 0; nt < 2; ++nt)
                bfr[nt] = *(const short8*)(p2w + ks * 1024 + nt * 512 + lane * 8);
            #pragma unroll
            for (int mt = 0; mt < 4; ++mt)
                #pragma unroll
                for (int nt = 0; nt < 2; ++nt)
                    acc2[mt][nt] = __builtin_amdgcn_mfma_f32_16x16x32_bf16(
                        af[mt], bfr[nt], acc2[mt][nt], 0, 0, 0);
        }
    }
    __syncthreads();   // aln/hidc dead -> ostage2 (full smem)

    #pragma unroll
    for (int mt = 0; mt < 4; ++mt)
        #pragma unroll
        for (int nt = 0; nt < 2; ++nt)
            #pragma unroll
            for (int r = 0; r < 4; ++r) {
                int m = mt * 16 + quad * 4 + r;
                int n = wv * 32 + nt * 16 + ln15;
                ostage[m * 132 + n] = acc2[mt][nt][r] + b2[n];
            }
    __syncthreads();

    // 6. final residual from regs + next-layer LN1 stats
    #pragma unroll
    for (int jj = 0; jj < 8; ++jj) {
        int idx = (jj * 256 + tid) * 4;
        int t = idx >> 7, c = idx & 127;
        float4 v = xm[jj];
        float4 o = *(const float4*)&ostage[t * 132 + c];
        v.x += o.x; v.y += o.y; v.z += o.z; v.w += o.w;
        *(float4*)(xbuf + tok0 * 128 + idx) = v;
        if (xout16) {
            __align__(8) bf16 hh[4];
            hh[0] = __float2bfloat16(v.x); hh[1] = __float2bfloat16(v.y);
            hh[2] = __float2bfloat16(v.z); hh[3] = __float2bfloat16(v.w);
            *(uint2*)(xout16 + tok0 * 128 + idx) = *(const uint2*)hh;
        }
        float ps = v.x + v.y + v.z + v.w;
        float pq = v.x * v.x + v.y * v.y + v.z * v.z + v.w * v.w;
        #pragma unroll
        for (int o2 = 16; o2 > 0; o2 >>= 1) {
            ps += __shfl_xor(ps, o2); pq += __shfl_xor(pq, o2);
        }
        if ((tid & 31) == 0) {
            float mu = ps * (1.0f / 128.0f);
            float var = pq * (1.0f / 128.0f) - mu * mu;
            size_t tok = tok0 + t;
            tstats[tok * 2]     = mu;
            tstats[tok * 2 + 1] = rsqrtf(var + 1e-5f);
        }
    }
}

// ---------------------------------------------------------------------------
// MFMA windowed attention (unchanged).
// ---------------------------------------------------------------------------
__global__ __launch_bounds__(256, 3) void attn_mfma_kernel(
    const bf16* __restrict__ qkv, const float* __restrict__ rpe,
    bf16* __restrict__ outp, int shift)
{
    __shared__ __align__(16) short qs[64 * 392];   // 49 KB; reused as O stage
    int tid = threadIdx.x;
    int lane = tid & 63, wv = tid >> 6;
    int ln15 = lane & 15, quad = lane >> 4;
    int win = blockIdx.x;
    size_t tok0 = (size_t)win * 64;

    const short* gq = (const short*)qkv + tok0 * 384;
    #pragma unroll
    for (int l = 0; l < 12; ++l) {
        int idx = l * 256 + tid;
        int r = idx / 48, c = idx - r * 48;
        *(uint4*)&qs[r * 392 + c * 8] = *(const uint4*)&gq[r * 384 + c * 8];
    }
    int w = win & 511;
    int wtype = 0;
    if (shift)
        wtype = (((w >> 6) == 7) << 2) | ((((w >> 3) & 7) == 7) << 1) | (int)((w & 7) == 7);
    const float* rpw = rpe + ((size_t)(wtype * 8) << 12);
    __syncthreads();

    floatx4 oacc[2][4];
    #pragma unroll
    for (int hh = 0; hh < 2; ++hh) {
        int head = wv * 2 + hh;
        const float* rph = rpw + ((size_t)head << 12);

        floatx4 acc[4][4];
        #pragma unroll
        for (int jt = 0; jt < 4; ++jt)
            #pragma unroll
            for (int it = 0; it < 4; ++it)
                acc[jt][it] = *(const floatx4*)&rph[(it * 16 + ln15) * 64 + jt * 16 + quad * 4];

        short4v qf[4], kf[4];
        #pragma unroll
        for (int it = 0; it < 4; ++it)
            qf[it] = *(const short4v*)&qs[(it * 16 + ln15) * 392 + head * 16 + quad * 4];
        #pragma unroll
        for (int jt = 0; jt < 4; ++jt)
            kf[jt] = *(const short4v*)&qs[(jt * 16 + ln15) * 392 + 128 + head * 16 + quad * 4];

        #pragma unroll
        for (int jt = 0; jt < 4; ++jt)
            #pragma unroll
            for (int it = 0; it < 4; ++it)
                acc[jt][it] = mfma16(kf[jt], qf[it], acc[jt][it]);

        short4v pf[4][4];
        #pragma unroll
        for (int it = 0; it < 4; ++it) {
            float m = -1e30f;
            #pragma unroll
            for (int jt = 0; jt < 4; ++jt)
                #pragma unroll
                for (int r = 0; r < 4; ++r) m = fmaxf(m, acc[jt][it][r]);
            m = fmaxf(m, __shfl_xor(m, 16));
            m = fmaxf(m, __shfl_xor(m, 32));
            float s = 0.f;
            #pragma unroll
            for (int jt = 0; jt < 4; ++jt)
                #pragma unroll
                for (int r = 0; r < 4; ++r) {
                    float e = __expf(acc[jt][it][r] - m);
                    acc[jt][it][r] = e; s += e;
                }
            s += __shfl_xor(s, 16);
            s += __shfl_xor(s, 32);
            float inv = 1.0f / s;
            #pragma unroll
            for (int jt = 0; jt < 4; ++jt) {
                __align__(8) bf16 pb[4];
                #pragma unroll
                for (int r = 0; r < 4; ++r)
                    pb[r] = __float2bfloat16(acc[jt][it][r] * inv);
                pf[jt][it] = *(const short4v*)pb;
            }
        }

        short4v vf[4];
        #pragma unroll
        for (int jt = 0; jt < 4; ++jt)
            #pragma unroll
            for (int jj = 0; jj < 4; ++jj)
                vf[jt][jj] = qs[(jt * 16 + quad * 4 + jj) * 392 + 256 + head * 16 + ln15];

        #pragma unroll
        for (int it = 0; it < 4; ++it) {
            floatx4 o = {0.f, 0.f, 0.f, 0.f};
            #pragma unroll
            for (int jt = 0; jt < 4; ++jt)
                o = mfma16(vf[jt], pf[jt][it], o);
            oacc[hh][it] = o;
        }
    }
    __syncthreads();   // all qs reads done -> reuse as O stage [64][136]

    short* ob = qs;
    #pragma unroll
    for (int hh = 0; hh < 2; ++hh)
        #pragma unroll
        for (int it = 0; it < 4; ++it) {
            __align__(8) bf16 t4[4];
            #pragma unroll
            for (int r = 0; r < 4; ++r) t4[r] = __float2bfloat16(oacc[hh][it][r]);
            *(short4v*)&ob[(it * 16 + ln15) * 136 + (wv * 2 + hh) * 16 + quad * 4] =
                *(const short4v*)t4;
        }
    __syncthreads();

    short* po = (short*)outp + tok0 * 128;
    #pragma unroll
    for (int l = 0; l < 4; ++l) {
        int idx = l * 256 + tid;
        int r = idx >> 4, c = idx & 15;
        *(uint4*)&po[r * 128 + c * 8] = *(const uint4*)&ob[r * 136 + c * 8];
    }
}

// ---------------------------------------------------------------------------
// Depthwise 3x3x3 conv v2 (unchanged).
// ---------------------------------------------------------------------------
__global__ __launch_bounds__(256) void dwconv_kernel(
    const bf16* __restrict__ x, const float* __restrict__ dwt,
    const float* __restrict__ bias, bf16* __restrict__ out)
{
    int blk = blockIdx.x;                  // b(1) | h(5) | wpair(4)
    int b = blk >> 9;
    int h = (blk >> 4) & 31;
    int w = ((blk & 15) << 1) | (threadIdx.x >> 7);
    int tid = threadIdx.x & 127;
    int c0 = (tid & 31) * 4;
    int t0 = (tid >> 5) * 8;

    float4 acc[8];
    float4 bs = *(const float4*)&bias[c0];
    #pragma unroll
    for (int o = 0; o < 8; ++o) acc[o] = bs;

    #pragma unroll
    for (int kh = 0; kh < 3; ++kh) {
        int hh = h + kh - 1;
        if (hh < 0 || hh > 31) continue;
        #pragma unroll
        for (int kw = 0; kw < 3; ++kw) {
            int ww = w + kw - 1;
            if (ww < 0 || ww > 31) continue;
            const short* px = (const short*)x +
                ((size_t)(b << 15) + (hh * 32 + ww) * 32) * 128 + c0;
            float4 v[10];
            #pragma unroll
            for (int u = 0; u < 10; ++u) {
                int tt = t0 - 1 + u;
                if (tt >= 0 && tt < 32) {
                    short4v s4 = *(const short4v*)(px + (size_t)tt * 128);
                    v[u].x = b2f(s4[0]); v[u].y = b2f(s4[1]);
                    v[u].z = b2f(s4[2]); v[u].w = b2f(s4[3]);
                } else {
                    v[u].x = v[u].y = v[u].z = v[u].w = 0.f;
                }
            }
            int kb = kh * 9 + kw * 3;
            float4 w0 = *(const float4*)&dwt[(kb + 0) * 128 + c0];
            float4 w1 = *(const float4*)&dwt[(kb + 1) * 128 + c0];
            float4 w2 = *(const float4*)&dwt[(kb + 2) * 128 + c0];
            #pragma unroll
            for (int o = 0; o < 8; ++o) {
                acc[o].x += v[o].x * w0.x + v[o + 1].x * w1.x + v[o + 2].x * w2.x;
                acc[o].y += v[o].y * w0.y + v[o + 1].y * w1.y + v[o + 2].y * w2.y;
                acc[o].z += v[o].z * w0.z + v[o + 1].z * w1.z + v[o + 2].z * w2.z;
                acc[o].w += v[o].w * w0.w + v[o + 1].w * w1.w + v[o + 2].w * w2.w;
            }
        }
    }
    short* po = (short*)out + ((size_t)(b << 15) + (h * 32 + w) * 32 + t0) * 128 + c0;
    #pragma unroll
    for (int o = 0; o < 8; ++o) {
        __align__(8) bf16 h4[4];
        h4[0] = __float2bfloat16(acc[o].x);
        h4[1] = __float2bfloat16(acc[o].y);
        h4[2] = __float2bfloat16(acc[o].z);
        h4[3] = __float2bfloat16(acc[o].w);
        *(uint2*)(po + (size_t)o * 128) = *(const uint2*)h4;
    }
}

// ---------------------------------------------------------------------------
extern "C" void kernel_launch(void* const* d_in, const int* in_sizes, int n_in,
                              void* d_out, int out_size, void* d_ws, size_t ws_size,
                              hipStream_t stream)
{
    const float* x_in    = (const float*)d_in[0];
    const float* norm1_g = (const float*)d_in[1];
    const float* norm1_b = (const float*)d_in[2];
    const float* qkv_w   = (const float*)d_in[3];
    const float* qkv_b   = (const float*)d_in[4];
    const float* proj_w  = (const float*)d_in[5];
    const float* proj_b  = (const float*)d_in[6];
    const float* rpb     = (const float*)d_in[7];
    const float* norm2_g = (const float*)d_in[8];
    const float* norm2_b = (const float*)d_in[9];
    const float* fc1_w   = (const float*)d_in[10];
    const float* fc1_b   = (const float*)d_in[11];
    const float* fc2_w   = (const float*)d_in[12];
    const float* fc2_b   = (const float*)d_in[13];
    const float* dw_w    = (const float*)d_in[14];
    const float* dw_b    = (const float*)d_in[15];
    const float* pw_w    = (const float*)d_in[16];
    const float* pw_b    = (const float*)d_in[17];
    const float* bn_g    = (const float*)d_in[18];
    const float* bn_b    = (const float*)d_in[19];
    float* out = (float*)d_out;

    char* ws = (char*)d_ws;
    float* xbuf   = (float*)ws;                          // [0,32MB)   fp32 [TOK,128]
    bf16*  wbf    = (bf16*)(ws + 33554432ULL);           // [32,34MB)  bf16 weights
    float* dwt    = (float*)(ws + 35651584ULL);          // 27x128 fp32
    float* stats  = (float*)(ws + 35717120ULL);          // 2 KB
    float* fb     = (float*)(ws + 35719168ULL);          // 14 KB folded biases
    bf16*  pw1    = (bf16*)(ws + 35782656ULL);           // 512 KB packed fc1
    bf16*  pw2    = (bf16*)(ws + 36306944ULL);           // 512 KB packed fc2
    float* tstats = (float*)(ws + 36831232ULL);          // 512 KB per-token LN stats
    bf16*  lnbuf  = (bf16*)(ws + 37748736ULL);           // [36,52MB)  rpe + dcbuf
    bf16*  attnbuf= (bf16*)(ws + 54525952ULL);           // [52,68MB)  [TOK,128]
    bf16*  qkvbuf = (bf16*)(ws + 71303168ULL);           // [68,116MB) [TOK,384]
    bf16*  dwbuf  = qkvbuf;          // last-layer bf16 out (qkvbuf dead by then)
    bf16*  dcbuf  = lnbuf;
    float* rpe    = (float*)lnbuf;   // 1 MB table in lnbuf region

    bf16* wqkv  = wbf;                 // 4 x 384 x 128 (gamma-folded)
    bf16* pproj = wbf + 196608;        // 4 x 16384 packed proj B-frags
    bf16* wpw   = wbf + 786432;        // 256 x 128

    hipLaunchKernelGGL(prep_kernel, dim3(3200), dim3(256), 0, stream,
                       qkv_w, proj_w, fc1_w, fc2_w, pw_w, dw_w, norm1_g,
                       wbf, dwt, stats);
    hipLaunchKernelGGL(foldbias_kernel, dim3(14), dim3(256), 0, stream,
                       qkv_w, qkv_b, norm1_b, fc1_w, fc1_b, norm2_b, fb);
    hipLaunchKernelGGL(pack_kernel, dim3(2048), dim3(256), 0, stream,
                       fc1_w, fc2_w, norm2_g, pw1, pw2);
    hipLaunchKernelGGL(transpose_in_kernel, dim3(1024), dim3(256), 0, stream,
                       x_in, xbuf, tstats);

    const int shifts[4] = {0, 2, 0, 2};
    for (int i = 0; i < 4; ++i) {
        int s = shifts[i];
        // --- attention half: LN (folded) fused into QKV GEMM ---
        hipLaunchKernelGGL(gemm_bf16_kernel, dim3(3, TOK / 128), dim3(256), 0, stream,
                           (const bf16*)nullptr, wqkv + (size_t)i * 49152, fb + i * 384,
                           qkvbuf, xbuf, tstats,
                           (const float*)nullptr, (const float*)nullptr,
                           TOK, 384, 128, 0, s);
        hipLaunchKernelGGL(rpe_expand_kernel, dim3(s ? 1024 : 128), dim3(256), 0, stream,
                           rpb, rpe, i);
        hipLaunchKernelGGL(attn_mfma_kernel, dim3(TOK / 64), dim3(256), 0, stream,
                           qkvbuf, rpe, attnbuf, s);
        // --- fused proj + residual + LN2 + MLP + next-layer LN1 stats ---
        hipLaunchKernelGGL(mlp_kernel, dim3(TOK / 64), dim3(256), 0, stream,
                           xbuf, attnbuf,
                           pproj + (size_t)i * 16384, proj_b + i * 128,
                           pw1 + (size_t)i * 65536, fb + 1536 + i * 512,
                           pw2 + (size_t)i * 65536, fc2_b + i * 128,
                           (i == 3) ? dwbuf : (bf16*)nullptr, tstats, s);
    }

    // connectBlock
    hipLaunchKernelGGL(dwconv_kernel, dim3(1024), dim3(256), 0, stream,
                       dwbuf, dwt, dw_b, dcbuf);
    hipLaunchKernelGGL(gemm_bf16_kernel, dim3(OUTC / 128, TOK / 128), dim3(256), 0, stream,
                       dcbuf, wpw, pw_b,
                       (bf16*)nullptr, (float*)nullptr, stats,
                       (const float*)nullptr, (const float*)nullptr,
                       TOK, OUTC, 128, 4, 0);
    hipLaunchKernelGGL(gemm_bf16_kernel, dim3(OUTC / 128, TOK / 128), dim3(256), 0, stream,
                       dcbuf, wpw, pw_b,
                       (bf16*)nullptr, out, stats,
                       bn_g, bn_b,
                       TOK, OUTC, 128, 5, 0);
}

// Round 10
// 700.981 us; speedup vs baseline: 1.0336x; 1.0336x over previous
//
#include <hip/hip_runtime.h>
#include <hip/hip_bf16.h>
#include <cstddef>
#include <cstdint>

typedef __attribute__((ext_vector_type(8))) short short8;
typedef __attribute__((ext_vector_type(4))) short short4v;
typedef __attribute__((ext_vector_type(4))) float floatx4;
typedef __hip_bfloat16 bf16;

#define HEADS 8
#define TOK   65536
#define OUTC  256

__device__ inline float b2f(short s) {
    union { unsigned u; float f; } x;
    x.u = ((unsigned)(unsigned short)s) << 16;
    return x.f;
}

// 16x16x16 bf16 MFMA. Builtin if present, else raw asm.
__device__ inline floatx4 mfma16(short4v a, short4v b, floatx4 c) {
#if __has_builtin(__builtin_amdgcn_mfma_f32_16x16x16bf16_1k)
    return __builtin_amdgcn_mfma_f32_16x16x16bf16_1k(a, b, c, 0, 0, 0);
#else
    floatx4 d;
    asm volatile("v_mfma_f32_16x16x16_bf16 %0, %1, %2, %3\n\ts_nop 7"
                 : "=v"(d) : "v"(a), "v"(b), "v"(c));
    return d;
#endif
}

// ---------------------------------------------------------------------------
// Transpose input (B,C,32,32,32) -> token-major xbuf[(b*32768+sp)*128 + c]
// + per-token LN stats (mu, rstd) for the layer-0 fused-LN QKV GEMM.
// ---------------------------------------------------------------------------
__global__ __launch_bounds__(256) void transpose_in_kernel(
    const float* __restrict__ x, float* __restrict__ out, float* __restrict__ tstats)
{
    __shared__ float tile[128 * 65];
    int chunk = blockIdx.x;
    int tid = threadIdx.x;
    int b = chunk >> 9;
    int sp0 = (chunk & 511) * 64;
    #pragma unroll
    for (int l = 0; l < 32; ++l) {
        int idx = l * 256 + tid;
        int c = idx >> 6;
        int s = idx & 63;
        tile[c * 65 + s] = x[(((size_t)(b * 128 + c)) << 15) + sp0 + s];
    }
    __syncthreads();
    #pragma unroll
    for (int l = 0; l < 32; ++l) {
        int idx = l * 256 + tid;
        int s = idx >> 7;
        int c = idx & 127;
        out[((size_t)((b << 15) + sp0 + s)) * 128 + c] = tile[c * 65 + s];
    }
    // per-token LN stats: 4 threads per token, 32 channels each
    int s = tid >> 2, q = tid & 3;
    float sm = 0.f, sq = 0.f;
    #pragma unroll
    for (int cc = 0; cc < 32; ++cc) {
        float v = tile[(q * 32 + cc) * 65 + s];
        sm += v; sq += v * v;
    }
    sm += __shfl_xor(sm, 1); sq += __shfl_xor(sq, 1);
    sm += __shfl_xor(sm, 2); sq += __shfl_xor(sq, 2);
    if (q == 0) {
        float mu = sm * (1.0f / 128.0f);
        float var = sq * (1.0f / 128.0f) - mu * mu;
        size_t tok = (size_t)(b << 15) + sp0 + s;
        tstats[tok * 2]     = mu;
        tstats[tok * 2 + 1] = rsqrtf(var + 1e-5f);
    }
}

// ---------------------------------------------------------------------------
// Prep: weight fp32->bf16 conversions + dw-weight transpose + stats zero.
// qkv weights are LN1-gamma-folded. proj weights are packed into MFMA
// B-fragment order for the fused proj+MLP kernel:
//   idx bits wv(2)|ks(2)|nt(1)|lane(6)|j(3) ->
//   proj_w[n = wv*32+nt*16+(lane&15)][k = ks*32+(lane>>4)*8+j]
// ---------------------------------------------------------------------------
__global__ __launch_bounds__(256) void prep_kernel(
    const float* __restrict__ qkv_w, const float* __restrict__ proj_w,
    const float* __restrict__ fc1_w, const float* __restrict__ fc2_w,
    const float* __restrict__ pw_w, const float* __restrict__ dw_w,
    const float* __restrict__ norm1_g,
    bf16* __restrict__ wbf, float* __restrict__ dwt, float* __restrict__ stats)
{
    int i = blockIdx.x * 256 + threadIdx.x;
    float v;
    if (i < 196608) {
        int layer = i / 49152, k = i & 127;
        v = qkv_w[i] * norm1_g[layer * 128 + k];
    }
    else if (i < 262144) {
        int jd = i - 196608;
        int layer = jd >> 14, idx = jd & 16383;
        int j = idx & 7, lane = (idx >> 3) & 63;
        int nt = (idx >> 9) & 1, ks = (idx >> 10) & 3, wvv = (idx >> 12) & 3;
        int row = wvv * 32 + nt * 16 + (lane & 15);
        int col = ks * 32 + (lane >> 4) * 8 + j;
        v = proj_w[layer * 16384 + row * 128 + col];
    }
    else if (i < 524288)  v = fc1_w[i - 262144];
    else if (i < 786432)  v = fc2_w[i - 524288];
    else                  v = pw_w[i - 786432];
    wbf[i] = __float2bfloat16(v);
    if (i < 3456) {
        int c = i / 27, k = i % 27;
        dwt[k * 128 + c] = dw_w[i];
    }
    if (i < 512) stats[i] = 0.f;
}

// ---------------------------------------------------------------------------
// Fold LN betas into biases:
//  fb[0..1536)  : qkvb[l][n]  = qkv_b + sum_k qkv_w[l][n][k]*norm1_b[l][k]
//  fb[1536..3584): b1f[l][n]  = fc1_b + sum_k fc1_w[l][n][k]*norm2_b[l][k]
// ---------------------------------------------------------------------------
__global__ __launch_bounds__(256) void foldbias_kernel(
    const float* __restrict__ qkv_w, const float* __restrict__ qkv_b,
    const float* __restrict__ norm1_b,
    const float* __restrict__ fc1_w, const float* __restrict__ fc1_b,
    const float* __restrict__ norm2_b, float* __restrict__ fb)
{
    int t = blockIdx.x * 256 + threadIdx.x;
    if (t < 1536) {
        int l = t / 384, n = t % 384;
        const float* wr = qkv_w + (size_t)l * 49152 + n * 128;
        const float* br = norm1_b + l * 128;
        float s = qkv_b[t];
        #pragma unroll 4
        for (int k = 0; k < 128; ++k) s += wr[k] * br[k];
        fb[t] = s;
    } else if (t < 3584) {
        int u = t - 1536;
        int l = u >> 9, n = u & 511;
        const float* wr = fc1_w + (size_t)l * 65536 + n * 128;
        const float* br = norm2_b + l * 128;
        float s = fc1_b[l * 512 + n];
        #pragma unroll 4
        for (int k = 0; k < 128; ++k) s += wr[k] * br[k];
        fb[t] = s;
    }
}

// ---------------------------------------------------------------------------
// Pack fc1/fc2 weights into MFMA-fragment order for the 4-chunk MLP.
// pw1 is LN2-gamma-folded (gamma indexes the k dimension = col).
// pw1 flat idx bits: cc(2)|wv(2)|kk(2)|nt(1)|lane(6)|j(3) ->
//   fc1_w[row = cc*128 + wv*32 + nt*16 + (lane&15)][col = kk*32 + (lane>>4)*8 + j]
// pw2 flat idx bits: wv(2)|cc(2)|ks(2)|nt(1)|lane(6)|j(3) ->
//   fc2_w[row = wv*32 + nt*16 + (lane&15)][col = cc*128 + ks*32 + (lane>>4)*8 + j]
// ---------------------------------------------------------------------------
__global__ __launch_bounds__(256) void pack_kernel(
    const float* __restrict__ fc1_w, const float* __restrict__ fc2_w,
    const float* __restrict__ norm2_g,
    bf16* __restrict__ pw1, bf16* __restrict__ pw2)
{
    int t = blockIdx.x * 256 + threadIdx.x;
    int i = t >> 17;
    int rem = t & 131071;
    int type = rem >> 16;
    int idx = rem & 65535;
    int j = idx & 7, lane = (idx >> 3) & 63;
    int ln15 = lane & 15, quad = lane >> 4;
    if (type == 0) {
        int nt = (idx >> 9) & 1, kk = (idx >> 10) & 3, wv = (idx >> 12) & 3, cc = (idx >> 14) & 3;
        int row = cc * 128 + wv * 32 + nt * 16 + ln15;
        int col = kk * 32 + quad * 8 + j;
        pw1[i * 65536 + idx] = __float2bfloat16(
            fc1_w[(size_t)i * 65536 + row * 128 + col] * norm2_g[i * 128 + col]);
    } else {
        int nt = (idx >> 9) & 1, ks = (idx >> 10) & 3, cc = (idx >> 12) & 3, wv = (idx >> 14) & 3;
        int row = wv * 32 + nt * 16 + ln15;
        int col = cc * 128 + ks * 32 + quad * 8 + j;
        pw2[i * 65536 + idx] = __float2bfloat16(fc2_w[(size_t)i * 65536 + row * 512 + col]);
    }
}

// ---------------------------------------------------------------------------
// Expand relative-position bias + shift mask into rpe[wtype][head][64][64] f32.
// ---------------------------------------------------------------------------
__global__ __launch_bounds__(256) void rpe_expand_kernel(
    const float* __restrict__ rpb, float* __restrict__ rpe, int layer)
{
    int t = blockIdx.x * 256 + threadIdx.x;
    int j = t & 63, i = (t >> 6) & 63, head = (t >> 12) & 7, wt = t >> 15;
    int ih = i >> 4, iw = (i >> 2) & 3, it = i & 3;
    int jh = j >> 4, jw = (j >> 2) & 3, jt = j & 3;
    int ridx = ((ih - jh + 3) * 7 + (iw - jw + 3)) * 7 + (it - jt + 3);
    float v = rpb[layer * 2744 + ridx * 8 + head];
    if (wt) {
        bool ok = true;
        if (wt & 4) ok = ok && ((ih >= 2) == (jh >= 2));
        if (wt & 2) ok = ok && ((iw >= 2) == (jw >= 2));
        if (wt & 1) ok = ok && ((it >= 2) == (jt >= 2));
        if (!ok) v -= 100.f;
    }
    rpe[t] = v;
}

// ---------------------------------------------------------------------------
// bf16 MFMA GEMM with coalesced LDS-staged epilogues.
// mode 0 (QKV): A-staging gathers fp32 rows from xbuf (Cf) with the shift-
// window token map and applies bf16((x-mu)*rstd) — gamma/beta folded into
// weights/bias. q columns (nBase==0) pre-scaled 0.25 in epilogue.
// mode 4/5: pointwise-conv stats / BN+ReLU epilogues (connectBlock).
// ---------------------------------------------------------------------------
__global__ __launch_bounds__(256) void gemm_bf16_kernel(
    const bf16* __restrict__ A, const bf16* __restrict__ Bw,
    const float* __restrict__ bias, bf16* __restrict__ Cb, float* __restrict__ Cf,
    float* __restrict__ aux, const float* __restrict__ p1, const float* __restrict__ p2,
    int M, int N, int K, int mode, int shift)
{
    __shared__ __align__(16) char smem[34816];
    __shared__ float cs[128];
    __shared__ float cq[128];
    short* As = (short*)smem;
    short* Bs = (short*)(smem + 8192);
    int tid = threadIdx.x;
    int lane = tid & 63, wv = tid >> 6;
    int wm = wv >> 1, wn = wv & 1;
    int ln15 = lane & 15, quad = lane >> 4;
    int q8 = quad * 8;
    int nBase = blockIdx.x * 128;
    int mBase = blockIdx.y * 128;
    floatx4 acc[4][4] = {};

    if (mode == 4 && tid < 128) { cs[tid] = 0.f; cq[tid] = 0.f; }

    int srow = tid >> 2, scb = tid & 3;

    int toks[2]; float tmu[2], trs[2];
    if (mode == 0) {
        #pragma unroll
        for (int i = 0; i < 2; ++i) {
            int m = mBase + srow + i * 64;
            int n = m & 63, w = (m >> 6) & 511, b = m >> 15;
            int ih = n >> 4, iw = (n >> 2) & 3, it = n & 3;
            int wh = w >> 6, ww = (w >> 3) & 7, wt = w & 7;
            int h  = (wh * 4 + ih + shift) & 31;
            int w2 = (ww * 4 + iw + shift) & 31;
            int t  = (wt * 4 + it + shift) & 31;
            toks[i] = (b << 15) + ((h * 32 + w2) * 32 + t);
            tmu[i] = aux[(size_t)toks[i] * 2];
            trs[i] = aux[(size_t)toks[i] * 2 + 1];
        }
    }

    for (int k0 = 0; k0 < K; k0 += 32) {
        if (mode == 0) {
            int cb = k0 + scb * 8;
            #pragma unroll
            for (int i = 0; i < 2; ++i) {
                const float* xr = Cf + (size_t)toks[i] * 128 + cb;
                float4 a0 = *(const float4*)xr;
                float4 a1 = *(const float4*)(xr + 4);
                float mu = tmu[i], rs = trs[i];
                __align__(16) bf16 pk[8];
                pk[0] = __float2bfloat16((a0.x - mu) * rs);
                pk[1] = __float2bfloat16((a0.y - mu) * rs);
                pk[2] = __float2bfloat16((a0.z - mu) * rs);
                pk[3] = __float2bfloat16((a0.w - mu) * rs);
                pk[4] = __float2bfloat16((a1.x - mu) * rs);
                pk[5] = __float2bfloat16((a1.y - mu) * rs);
                pk[6] = __float2bfloat16((a1.z - mu) * rs);
                pk[7] = __float2bfloat16((a1.w - mu) * rs);
                ((uint4*)As)[i * 256 + tid] = *(const uint4*)pk;
                ((uint4*)Bs)[i * 256 + tid] =
                    *(const uint4*)(Bw + (size_t)(nBase + srow + i * 64) * K + cb);
            }
        } else {
            #pragma unroll
            for (int i = 0; i < 2; ++i) {
                int row = srow + i * 64;
                ((uint4*)As)[i * 256 + tid] =
                    *(const uint4*)(A + (size_t)(mBase + row) * K + k0 + scb * 8);
                ((uint4*)Bs)[i * 256 + tid] =
                    *(const uint4*)(Bw + (size_t)(nBase + row) * K + k0 + scb * 8);
            }
        }
        __syncthreads();
        short8 af[4], bfr[4];
        #pragma unroll
        for (int mt = 0; mt < 4; ++mt)
            af[mt] = *(const short8*)&As[(wm * 64 + mt * 16 + ln15) * 32 + q8];
        #pragma unroll
        for (int nt = 0; nt < 4; ++nt)
            bfr[nt] = *(const short8*)&Bs[(wn * 64 + nt * 16 + ln15) * 32 + q8];
        #pragma unroll
        for (int mt = 0; mt < 4; ++mt)
            #pragma unroll
            for (int nt = 0; nt < 4; ++nt)
                acc[mt][nt] = __builtin_amdgcn_mfma_f32_16x16x32_bf16(
                    af[mt], bfr[nt], acc[mt][nt], 0, 0, 0);
        __syncthreads();
    }

    if (mode == 4) {
        #pragma unroll
        for (int nt = 0; nt < 4; ++nt) {
            int nl = wn * 64 + nt * 16 + ln15;
            float bs = bias[nBase + nl];
            float s = 0.f, sq = 0.f;
            #pragma unroll
            for (int mt = 0; mt < 4; ++mt)
                #pragma unroll
                for (int r = 0; r < 4; ++r) {
                    float v = acc[mt][nt][r] + bs;
                    s += v; sq += v * v;
                }
            atomicAdd(&cs[nl], s);
            atomicAdd(&cq[nl], sq);
        }
        __syncthreads();
        if (tid < 128) {
            atomicAdd(&aux[nBase + tid], cs[tid]);
            atomicAdd(&aux[256 + nBase + tid], cq[tid]);
        }
        return;
    }

    if (mode == 0) {
        bf16* estage = (bf16*)smem;          // [128][136]
        float qsc = (nBase == 0) ? 0.25f : 1.0f;
        #pragma unroll
        for (int mt = 0; mt < 4; ++mt)
            #pragma unroll
            for (int nt = 0; nt < 4; ++nt)
                #pragma unroll
                for (int r = 0; r < 4; ++r) {
                    int row = wm * 64 + mt * 16 + quad * 4 + r;
                    int col = wn * 64 + nt * 16 + ln15;
                    estage[row * 136 + col] =
                        __float2bfloat16((acc[mt][nt][r] + bias[nBase + col]) * qsc);
                }
        __syncthreads();
        int row = tid >> 1, hf = tid & 1;
        #pragma unroll
        for (int j = 0; j < 4; ++j) {
            int col = hf * 64 + j * 16;
            *(uint4*)(Cb + (size_t)(mBase + row) * N + nBase + col) =
                *(const uint4*)&estage[row * 136 + col];
            *(uint4*)(Cb + (size_t)(mBase + row) * N + nBase + col + 8) =
                *(const uint4*)&estage[row * 136 + col + 8];
        }
        return;
    }

    // mode 5: BN + ReLU + transposed store
    {
        float* fstage = (float*)smem;        // [64 nn][132 sp]
        int b = mBase >> 15, sp0 = mBase & 32767;
        #pragma unroll
        for (int hf = 0; hf < 2; ++hf) {
            if (wn == hf) {
                #pragma unroll
                for (int nt = 0; nt < 4; ++nt) {
                    int ncol = nt * 16 + ln15;
                    int nn = nBase + hf * 64 + ncol;
                    float mean = aux[nn] * (1.0f / 65536.0f);
                    float var  = aux[256 + nn] * (1.0f / 65536.0f) - mean * mean;
                    float sc = rsqrtf(var + 1e-5f) * p1[nn];
                    float off = p2[nn] + bias[nn] * sc - mean * sc;
                    #pragma unroll
                    for (int mt = 0; mt < 4; ++mt)
                        #pragma unroll
                        for (int r = 0; r < 4; ++r) {
                            int ml = wm * 64 + mt * 16 + quad * 4 + r;
                            float y = acc[mt][nt][r] * sc + off;
                            fstage[ncol * 132 + ml] = fmaxf(y, 0.f);
                        }
                }
            }
            __syncthreads();
            int nl = tid >> 2, part = tid & 3;
            int nn = nBase + hf * 64 + nl;
            float* dst = Cf + (((size_t)(b * 256 + nn)) << 15) + sp0 + part * 32;
            #pragma unroll
            for (int j = 0; j < 8; ++j)
                *(float4*)(dst + j * 4) = *(const float4*)&fstage[nl * 132 + part * 32 + j * 4];
            __syncthreads();
        }
    }
}

// ---------------------------------------------------------------------------
// Fused proj + residual + LN2 + MLP (v7.2). Each block = 64 natural-order
// tokens. x_mid is ROUND-TRIPPED through xbuf (L2-resident) instead of held
// in registers: the 32-VGPR xm live range made the allocator spill to
// scratch at any launch_bounds (R8: 53 MB/dispatch at (256,4); R9: 22 MB at
// (256,3) + occupancy loss). Step 3 writes x_mid to xbuf + LN stats to tmr;
// steps 4/6 re-read the thread's own xbuf lines (no cross-thread dep).
// Spill-free at (256,4): 4 blocks/CU, LDS 4x34.5 KB = 138 KB.
// ---------------------------------------------------------------------------
__global__ __launch_bounds__(256, 4) void mlp_kernel(
    float* __restrict__ xbuf, const bf16* __restrict__ attnbuf,
    const bf16* __restrict__ ppw, const float* __restrict__ pb,
    const bf16* __restrict__ pw1, const float* __restrict__ b1,
    const bf16* __restrict__ pw2, const float* __restrict__ b2,
    bf16* __restrict__ xout16, float* __restrict__ tstats, int shift)
{
    __shared__ __align__(16) bf16 smem[64 * 136 * 2];   // 34 KB
    __shared__ float tmr[128];                          // 64 tokens x {mu, rs}
    bf16* aln  = smem;              // [64][136] atile / LN2'd x_mid
    bf16* hidc = smem + 64 * 136;   // [64][136] per-chunk hidden
    float* ostage = (float*)smem;   // [64][132] f32, full-smem alias
    int tid = threadIdx.x;
    int lane = tid & 63, wv = tid >> 6;
    int ln15 = lane & 15, quad = lane >> 4;
    int q8 = quad * 8;
    int blk = blockIdx.x;
    size_t tok0 = (size_t)blk * 64;
    int b = blk >> 9, h = (blk >> 4) & 31, wpair = blk & 15;

    // 1. gather attnbuf (window order) -> atile rows in natural-local order
    #pragma unroll
    for (int l = 0; l < 4; ++l) {
        int q = l * 256 + tid;
        int row = q >> 4, c16 = q & 15;
        int w2 = wpair * 2 + (row >> 5), t = row & 31;
        int hs = (h - shift) & 31, ws = (w2 - shift) & 31, ts = (t - shift) & 31;
        int wr = (b << 15) + (((hs >> 2) * 64 + ((ws >> 2) << 3) + (ts >> 2)) << 6)
               + ((hs & 3) * 16 + ((ws & 3) << 2) + (ts & 3));
        *(uint4*)&aln[row * 136 + c16 * 8] =
            *(const uint4*)((const short*)attnbuf + (size_t)wr * 128 + c16 * 8);
    }
    __syncthreads();

    // 2. proj: out[64][128]; wave wv -> cols wv*32..+31, K=128
    floatx4 accp[4][2] = {};
    #pragma unroll
    for (int ks = 0; ks < 4; ++ks) {
        short8 af[4], bfr[2];
        #pragma unroll
        for (int mt = 0; mt < 4; ++mt)
            af[mt] = *(const short8*)&aln[(mt * 16 + ln15) * 136 + ks * 32 + q8];
        #pragma unroll
        for (int nt = 0; nt < 2; ++nt)
            bfr[nt] = *(const short8*)(ppw + wv * 4096 + ks * 1024 + nt * 512 + lane * 8);
        #pragma unroll
        for (int mt = 0; mt < 4; ++mt)
            #pragma unroll
            for (int nt = 0; nt < 2; ++nt)
                accp[mt][nt] = __builtin_amdgcn_mfma_f32_16x16x32_bf16(
                    af[mt], bfr[nt], accp[mt][nt], 0, 0, 0);
    }
    __syncthreads();   // atile dead -> ostage (full smem)

    #pragma unroll
    for (int mt = 0; mt < 4; ++mt)
        #pragma unroll
        for (int nt = 0; nt < 2; ++nt)
            #pragma unroll
            for (int r = 0; r < 4; ++r) {
                int m = mt * 16 + quad * 4 + r;
                int n = wv * 32 + nt * 16 + ln15;
                ostage[m * 132 + n] = accp[mt][nt][r] + pb[n];
            }
    __syncthreads();

    // 3. x_mid = xbuf + proj -> write back to xbuf; LN2 stats -> tmr
    #pragma unroll
    for (int jj = 0; jj < 8; ++jj) {
        int idx = (jj * 256 + tid) * 4;
        int t = idx >> 7, c = idx & 127;
        float4 v = *(const float4*)(xbuf + tok0 * 128 + idx);
        float4 o = *(const float4*)&ostage[t * 132 + c];
        v.x += o.x; v.y += o.y; v.z += o.z; v.w += o.w;
        *(float4*)(xbuf + tok0 * 128 + idx) = v;
        float ps = v.x + v.y + v.z + v.w;
        float pq = v.x * v.x + v.y * v.y + v.z * v.z + v.w * v.w;
        #pragma unroll
        for (int o2 = 16; o2 > 0; o2 >>= 1) {
            ps += __shfl_xor(ps, o2); pq += __shfl_xor(pq, o2);
        }
        if ((tid & 31) == 0) {
            float mu = ps * (1.0f / 128.0f);
            float var = pq * (1.0f / 128.0f) - mu * mu;
            tmr[t * 2]     = mu;
            tmr[t * 2 + 1] = rsqrtf(var + 1e-5f);
        }
    }
    __syncthreads();   // all ostage reads done -> aln reusable

    // 4. LN2: re-read own x_mid lines (L2-hot), normalize -> aln bf16
    #pragma unroll
    for (int jj = 0; jj < 8; ++jj) {
        int idx = (jj * 256 + tid) * 4;
        int t = idx >> 7, c = idx & 127;
        float4 v = *(const float4*)(xbuf + tok0 * 128 + idx);
        float mu = tmr[t * 2], rs = tmr[t * 2 + 1];
        __align__(8) bf16 hh[4];
        hh[0] = __float2bfloat16((v.x - mu) * rs);
        hh[1] = __float2bfloat16((v.y - mu) * rs);
        hh[2] = __float2bfloat16((v.z - mu) * rs);
        hh[3] = __float2bfloat16((v.w - mu) * rs);
        *(uint2*)&aln[t * 136 + c] = *(const uint2*)hh;
    }
    __syncthreads();

    // 5. 4-chunk MLP (R5-proven)
    floatx4 acc2[4][2] = {};
    #pragma unroll
    for (int cc = 0; cc < 4; ++cc) {
        floatx4 acc[4][2] = {};
        const bf16* p1w = pw1 + (size_t)(cc * 4 + wv) * 4096;
        #pragma unroll
        for (int kk = 0; kk < 4; ++kk) {
            short8 af[4], bfr[2];
            #pragma unroll
            for (int mt = 0; mt < 4; ++mt)
                af[mt] = *(const short8*)&aln[(mt * 16 + ln15) * 136 + kk * 32 + q8];
            #pragma unroll
            for (int nt = 0; nt < 2; ++nt)
                bfr[nt] = *(const short8*)(p1w + kk * 1024 + nt * 512 + lane * 8);
            #pragma unroll
            for (int mt = 0; mt < 4; ++mt)
                #pragma unroll
                for (int nt = 0; nt < 2; ++nt)
                    acc[mt][nt] = __builtin_amdgcn_mfma_f32_16x16x32_bf16(
                        af[mt], bfr[nt], acc[mt][nt], 0, 0, 0);
        }
        if (cc) __syncthreads();
        #pragma unroll
        for (int mt = 0; mt < 4; ++mt)
            #pragma unroll
            for (int nt = 0; nt < 2; ++nt)
                #pragma unroll
                for (int r = 0; r < 4; ++r) {
                    int m = mt * 16 + quad * 4 + r;
                    int ncl = wv * 32 + nt * 16 + ln15;
                    float v = acc[mt][nt][r] + b1[cc * 128 + ncl];
                    float u = v * (0.7978845608f + 0.0356774081f * v * v);
                    v = v * __builtin_amdgcn_rcpf(1.f + __expf(-2.f * u));
                    hidc[m * 136 + ncl] = __float2bfloat16(v);
                }
        __syncthreads();
        const bf16* p2w = pw2 + (size_t)(wv * 4 + cc) * 4096;
        #pragma unroll
        for (int ks = 0; ks < 4; ++ks) {
            short8 af[4], bfr[2];
            #pragma unroll
            for (int mt = 0; mt < 4; ++mt)
                af[mt] = *(const short8*)&hidc[(mt * 16 + ln15) * 136 + ks * 32 + q8];
            #pragma unroll
            for (int nt = 0; nt < 2; ++nt)
                bfr[nt] = *(const short8*)(p2w + ks * 1024 + nt * 512 + lane * 8);
            #pragma unroll
            for (int mt = 0; mt < 4; ++mt)
                #pragma unroll
                for (int nt = 0; nt < 2; ++nt)
                    acc2[mt][nt] = __builtin_amdgcn_mfma_f32_16x16x32_bf16(
                        af[mt], bfr[nt], acc2[mt][nt], 0, 0, 0);
        }
    }
    __syncthreads();   // aln/hidc dead -> ostage2 (full smem)

    #pragma unroll
    for (int mt = 0; mt < 4; ++mt)
        #pragma unroll
        for (int nt = 0; nt < 2; ++nt)
            #pragma unroll
            for (int r = 0; r < 4; ++r) {
                int m = mt * 16 + quad * 4 + r;
                int n = wv * 32 + nt * 16 + ln15;
                ostage[m * 132 + n] = acc2[mt][nt][r] + b2[n];
            }
    __syncthreads();

    // 6. final residual: re-read own x_mid lines + MLP out; next-layer stats
    #pragma unroll
    for (int jj = 0; jj < 8; ++jj) {
        int idx = (jj * 256 + tid) * 4;
        int t = idx >> 7, c = idx & 127;
        float4 v = *(const float4*)(xbuf + tok0 * 128 + idx);
        float4 o = *(const float4*)&ostage[t * 132 + c];
        v.x += o.x; v.y += o.y; v.z += o.z; v.w += o.w;
        *(float4*)(xbuf + tok0 * 128 + idx) = v;
        if (xout16) {
            __align__(8) bf16 hh[4];
            hh[0] = __float2bfloat16(v.x); hh[1] = __float2bfloat16(v.y);
            hh[2] = __float2bfloat16(v.z); hh[3] = __float2bfloat16(v.w);
            *(uint2*)(xout16 + tok0 * 128 + idx) = *(const uint2*)hh;
        }
        float ps = v.x + v.y + v.z + v.w;
        float pq = v.x * v.x + v.y * v.y + v.z * v.z + v.w * v.w;
        #pragma unroll
        for (int o2 = 16; o2 > 0; o2 >>= 1) {
            ps += __shfl_xor(ps, o2); pq += __shfl_xor(pq, o2);
        }
        if ((tid & 31) == 0) {
            float mu = ps * (1.0f / 128.0f);
            float var = pq * (1.0f / 128.0f) - mu * mu;
            size_t tok = tok0 + t;
            tstats[tok * 2]     = mu;
            tstats[tok * 2 + 1] = rsqrtf(var + 1e-5f);
        }
    }
}

// ---------------------------------------------------------------------------
// MFMA windowed attention (unchanged).
// ---------------------------------------------------------------------------
__global__ __launch_bounds__(256, 3) void attn_mfma_kernel(
    const bf16* __restrict__ qkv, const float* __restrict__ rpe,
    bf16* __restrict__ outp, int shift)
{
    __shared__ __align__(16) short qs[64 * 392];   // 49 KB; reused as O stage
    int tid = threadIdx.x;
    int lane = tid & 63, wv = tid >> 6;
    int ln15 = lane & 15, quad = lane >> 4;
    int win = blockIdx.x;
    size_t tok0 = (size_t)win * 64;

    const short* gq = (const short*)qkv + tok0 * 384;
    #pragma unroll
    for (int l = 0; l < 12; ++l) {
        int idx = l * 256 + tid;
        int r = idx / 48, c = idx - r * 48;
        *(uint4*)&qs[r * 392 + c * 8] = *(const uint4*)&gq[r * 384 + c * 8];
    }
    int w = win & 511;
    int wtype = 0;
    if (shift)
        wtype = (((w >> 6) == 7) << 2) | ((((w >> 3) & 7) == 7) << 1) | (int)((w & 7) == 7);
    const float* rpw = rpe + ((size_t)(wtype * 8) << 12);
    __syncthreads();

    floatx4 oacc[2][4];
    #pragma unroll
    for (int hh = 0; hh < 2; ++hh) {
        int head = wv * 2 + hh;
        const float* rph = rpw + ((size_t)head << 12);

        floatx4 acc[4][4];
        #pragma unroll
        for (int jt = 0; jt < 4; ++jt)
            #pragma unroll
            for (int it = 0; it < 4; ++it)
                acc[jt][it] = *(const floatx4*)&rph[(it * 16 + ln15) * 64 + jt * 16 + quad * 4];

        short4v qf[4], kf[4];
        #pragma unroll
        for (int it = 0; it < 4; ++it)
            qf[it] = *(const short4v*)&qs[(it * 16 + ln15) * 392 + head * 16 + quad * 4];
        #pragma unroll
        for (int jt = 0; jt < 4; ++jt)
            kf[jt] = *(const short4v*)&qs[(jt * 16 + ln15) * 392 + 128 + head * 16 + quad * 4];

        #pragma unroll
        for (int jt = 0; jt < 4; ++jt)
            #pragma unroll
            for (int it = 0; it < 4; ++it)
                acc[jt][it] = mfma16(kf[jt], qf[it], acc[jt][it]);

        short4v pf[4][4];
        #pragma unroll
        for (int it = 0; it < 4; ++it) {
            float m = -1e30f;
            #pragma unroll
            for (int jt = 0; jt < 4; ++jt)
                #pragma unroll
                for (int r = 0; r < 4; ++r) m = fmaxf(m, acc[jt][it][r]);
            m = fmaxf(m, __shfl_xor(m, 16));
            m = fmaxf(m, __shfl_xor(m, 32));
            float s = 0.f;
            #pragma unroll
            for (int jt = 0; jt < 4; ++jt)
                #pragma unroll
                for (int r = 0; r < 4; ++r) {
                    float e = __expf(acc[jt][it][r] - m);
                    acc[jt][it][r] = e; s += e;
                }
            s += __shfl_xor(s, 16);
            s += __shfl_xor(s, 32);
            float inv = 1.0f / s;
            #pragma unroll
            for (int jt = 0; jt < 4; ++jt) {
                __align__(8) bf16 pb[4];
                #pragma unroll
                for (int r = 0; r < 4; ++r)
                    pb[r] = __float2bfloat16(acc[jt][it][r] * inv);
                pf[jt][it] = *(const short4v*)pb;
            }
        }

        short4v vf[4];
        #pragma unroll
        for (int jt = 0; jt < 4; ++jt)
            #pragma unroll
            for (int jj = 0; jj < 4; ++jj)
                vf[jt][jj] = qs[(jt * 16 + quad * 4 + jj) * 392 + 256 + head * 16 + ln15];

        #pragma unroll
        for (int it = 0; it < 4; ++it) {
            floatx4 o = {0.f, 0.f, 0.f, 0.f};
            #pragma unroll
            for (int jt = 0; jt < 4; ++jt)
                o = mfma16(vf[jt], pf[jt][it], o);
            oacc[hh][it] = o;
        }
    }
    __syncthreads();   // all qs reads done -> reuse as O stage [64][136]

    short* ob = qs;
    #pragma unroll
    for (int hh = 0; hh < 2; ++hh)
        #pragma unroll
        for (int it = 0; it < 4; ++it) {
            __align__(8) bf16 t4[4];
            #pragma unroll
            for (int r = 0; r < 4; ++r) t4[r] = __float2bfloat16(oacc[hh][it][r]);
            *(short4v*)&ob[(it * 16 + ln15) * 136 + (wv * 2 + hh) * 16 + quad * 4] =
                *(const short4v*)t4;
        }
    __syncthreads();

    short* po = (short*)outp + tok0 * 128;
    #pragma unroll
    for (int l = 0; l < 4; ++l) {
        int idx = l * 256 + tid;
        int r = idx >> 4, c = idx & 15;
        *(uint4*)&po[r * 128 + c * 8] = *(const uint4*)&ob[r * 136 + c * 8];
    }
}

// ---------------------------------------------------------------------------
// Depthwise 3x3x3 conv v2 (unchanged).
// ---------------------------------------------------------------------------
__global__ __launch_bounds__(256) void dwconv_kernel(
    const bf16* __restrict__ x, const float* __restrict__ dwt,
    const float* __restrict__ bias, bf16* __restrict__ out)
{
    int blk = blockIdx.x;                  // b(1) | h(5) | wpair(4)
    int b = blk >> 9;
    int h = (blk >> 4) & 31;
    int w = ((blk & 15) << 1) | (threadIdx.x >> 7);
    int tid = threadIdx.x & 127;
    int c0 = (tid & 31) * 4;
    int t0 = (tid >> 5) * 8;

    float4 acc[8];
    float4 bs = *(const float4*)&bias[c0];
    #pragma unroll
    for (int o = 0; o < 8; ++o) acc[o] = bs;

    #pragma unroll
    for (int kh = 0; kh < 3; ++kh) {
        int hh = h + kh - 1;
        if (hh < 0 || hh > 31) continue;
        #pragma unroll
        for (int kw = 0; kw < 3; ++kw) {
            int ww = w + kw - 1;
            if (ww < 0 || ww > 31) continue;
            const short* px = (const short*)x +
                ((size_t)(b << 15) + (hh * 32 + ww) * 32) * 128 + c0;
            float4 v[10];
            #pragma unroll
            for (int u = 0; u < 10; ++u) {
                int tt = t0 - 1 + u;
                if (tt >= 0 && tt < 32) {
                    short4v s4 = *(const short4v*)(px + (size_t)tt * 128);
                    v[u].x = b2f(s4[0]); v[u].y = b2f(s4[1]);
                    v[u].z = b2f(s4[2]); v[u].w = b2f(s4[3]);
                } else {
                    v[u].x = v[u].y = v[u].z = v[u].w = 0.f;
                }
            }
            int kb = kh * 9 + kw * 3;
            float4 w0 = *(const float4*)&dwt[(kb + 0) * 128 + c0];
            float4 w1 = *(const float4*)&dwt[(kb + 1) * 128 + c0];
            float4 w2 = *(const float4*)&dwt[(kb + 2) * 128 + c0];
            #pragma unroll
            for (int o = 0; o < 8; ++o) {
                acc[o].x += v[o].x * w0.x + v[o + 1].x * w1.x + v[o + 2].x * w2.x;
                acc[o].y += v[o].y * w0.y + v[o + 1].y * w1.y + v[o + 2].y * w2.y;
                acc[o].z += v[o].z * w0.z + v[o + 1].z * w1.z + v[o + 2].z * w2.z;
                acc[o].w += v[o].w * w0.w + v[o + 1].w * w1.w + v[o + 2].w * w2.w;
            }
        }
    }
    short* po = (short*)out + ((size_t)(b << 15) + (h * 32 + w) * 32 + t0) * 128 + c0;
    #pragma unroll
    for (int o = 0; o < 8; ++o) {
        __align__(8) bf16 h4[4];
        h4[0] = __float2bfloat16(acc[o].x);
        h4[1] = __float2bfloat16(acc[o].y);
        h4[2] = __float2bfloat16(acc[o].z);
        h4[3] = __float2bfloat16(acc[o].w);
        *(uint2*)(po + (size_t)o * 128) = *(const uint2*)h4;
    }
}

// ---------------------------------------------------------------------------
extern "C" void kernel_launch(void* const* d_in, const int* in_sizes, int n_in,
                              void* d_out, int out_size, void* d_ws, size_t ws_size,
                              hipStream_t stream)
{
    const float* x_in    = (const float*)d_in[0];
    const float* norm1_g = (const float*)d_in[1];
    const float* norm1_b = (const float*)d_in[2];
    const float* qkv_w   = (const float*)d_in[3];
    const float* qkv_b   = (const float*)d_in[4];
    const float* proj_w  = (const float*)d_in[5];
    const float* proj_b  = (const float*)d_in[6];
    const float* rpb     = (const float*)d_in[7];
    const float* norm2_g = (const float*)d_in[8];
    const float* norm2_b = (const float*)d_in[9];
    const float* fc1_w   = (const float*)d_in[10];
    const float* fc1_b   = (const float*)d_in[11];
    const float* fc2_w   = (const float*)d_in[12];
    const float* fc2_b   = (const float*)d_in[13];
    const float* dw_w    = (const float*)d_in[14];
    const float* dw_b    = (const float*)d_in[15];
    const float* pw_w    = (const float*)d_in[16];
    const float* pw_b    = (const float*)d_in[17];
    const float* bn_g    = (const float*)d_in[18];
    const float* bn_b    = (const float*)d_in[19];
    float* out = (float*)d_out;

    char* ws = (char*)d_ws;
    float* xbuf   = (float*)ws;                          // [0,32MB)   fp32 [TOK,128]
    bf16*  wbf    = (bf16*)(ws + 33554432ULL);           // [32,34MB)  bf16 weights
    float* dwt    = (float*)(ws + 35651584ULL);          // 27x128 fp32
    float* stats  = (float*)(ws + 35717120ULL);          // 2 KB
    float* fb     = (float*)(ws + 35719168ULL);          // 14 KB folded biases
    bf16*  pw1    = (bf16*)(ws + 35782656ULL);           // 512 KB packed fc1
    bf16*  pw2    = (bf16*)(ws + 36306944ULL);           // 512 KB packed fc2
    float* tstats = (float*)(ws + 36831232ULL);          // 512 KB per-token LN stats
    bf16*  lnbuf  = (bf16*)(ws + 37748736ULL);           // [36,52MB)  rpe + dcbuf
    bf16*  attnbuf= (bf16*)(ws + 54525952ULL);           // [52,68MB)  [TOK,128]
    bf16*  qkvbuf = (bf16*)(ws + 71303168ULL);           // [68,116MB) [TOK,384]
    bf16*  dwbuf  = qkvbuf;          // last-layer bf16 out (qkvbuf dead by then)
    bf16*  dcbuf  = lnbuf;
    float* rpe    = (float*)lnbuf;   // 1 MB table in lnbuf region

    bf16* wqkv  = wbf;                 // 4 x 384 x 128 (gamma-folded)
    bf16* pproj = wbf + 196608;        // 4 x 16384 packed proj B-frags
    bf16* wpw   = wbf + 786432;        // 256 x 128

    hipLaunchKernelGGL(prep_kernel, dim3(3200), dim3(256), 0, stream,
                       qkv_w, proj_w, fc1_w, fc2_w, pw_w, dw_w, norm1_g,
                       wbf, dwt, stats);
    hipLaunchKernelGGL(foldbias_kernel, dim3(14), dim3(256), 0, stream,
                       qkv_w, qkv_b, norm1_b, fc1_w, fc1_b, norm2_b, fb);
    hipLaunchKernelGGL(pack_kernel, dim3(2048), dim3(256), 0, stream,
                       fc1_w, fc2_w, norm2_g, pw1, pw2);
    hipLaunchKernelGGL(transpose_in_kernel, dim3(1024), dim3(256), 0, stream,
                       x_in, xbuf, tstats);

    const int shifts[4] = {0, 2, 0, 2};
    for (int i = 0; i < 4; ++i) {
        int s = shifts[i];
        // --- attention half: LN (folded) fused into QKV GEMM ---
        hipLaunchKernelGGL(gemm_bf16_kernel, dim3(3, TOK / 128), dim3(256), 0, stream,
                           (const bf16*)nullptr, wqkv + (size_t)i * 49152, fb + i * 384,
                           qkvbuf, xbuf, tstats,
                           (const float*)nullptr, (const float*)nullptr,
                           TOK, 384, 128, 0, s);
        hipLaunchKernelGGL(rpe_expand_kernel, dim3(s ? 1024 : 128), dim3(256), 0, stream,
                           rpb, rpe, i);
        hipLaunchKernelGGL(attn_mfma_kernel, dim3(TOK / 64), dim3(256), 0, stream,
                           qkvbuf, rpe, attnbuf, s);
        // --- fused proj + residual + LN2 + MLP + next-layer LN1 stats ---
        hipLaunchKernelGGL(mlp_kernel, dim3(TOK / 64), dim3(256), 0, stream,
                           xbuf, attnbuf,
                           pproj + (size_t)i * 16384, proj_b + i * 128,
                           pw1 + (size_t)i * 65536, fb + 1536 + i * 512,
                           pw2 + (size_t)i * 65536, fc2_b + i * 128,
                           (i == 3) ? dwbuf : (bf16*)nullptr, tstats, s);
    }

    // connectBlock
    hipLaunchKernelGGL(dwconv_kernel, dim3(1024), dim3(256), 0, stream,
                       dwbuf, dwt, dw_b, dcbuf);
    hipLaunchKernelGGL(gemm_bf16_kernel, dim3(OUTC / 128, TOK / 128), dim3(256), 0, stream,
                       dcbuf, wpw, pw_b,
                       (bf16*)nullptr, (float*)nullptr, stats,
                       (const float*)nullptr, (const float*)nullptr,
                       TOK, OUTC, 128, 4, 0);
    hipLaunchKernelGGL(gemm_bf16_kernel, dim3(OUTC / 128, TOK / 128), dim3(256), 0, stream,
                       dcbuf, wpw, pw_b,
                       (bf16*)nullptr, out, stats,
                       bn_g, bn_b,
                       TOK, OUTC, 128, 5, 0);
}

// Round 11
// 677.847 us; speedup vs baseline: 1.0688x; 1.0341x over previous
//
#include <hip/hip_runtime.h>
#include <hip/hip_bf16.h>
#include <cstddef>
#include <cstdint>

typedef __attribute__((ext_vector_type(8))) short short8;
typedef __attribute__((ext_vector_type(4))) short short4v;
typedef __attribute__((ext_vector_type(4))) float floatx4;
typedef __hip_bfloat16 bf16;

#define HEADS 8
#define TOK   65536
#define OUTC  256

__device__ inline float b2f(short s) {
    union { unsigned u; float f; } x;
    x.u = ((unsigned)(unsigned short)s) << 16;
    return x.f;
}

// 16x16x16 bf16 MFMA. Builtin if present, else raw asm.
__device__ inline floatx4 mfma16(short4v a, short4v b, floatx4 c) {
#if __has_builtin(__builtin_amdgcn_mfma_f32_16x16x16bf16_1k)
    return __builtin_amdgcn_mfma_f32_16x16x16bf16_1k(a, b, c, 0, 0, 0);
#else
    floatx4 d;
    asm volatile("v_mfma_f32_16x16x16_bf16 %0, %1, %2, %3\n\ts_nop 7"
                 : "=v"(d) : "v"(a), "v"(b), "v"(c));
    return d;
#endif
}

// ---------------------------------------------------------------------------
// Transpose input (B,C,32,32,32) -> token-major xbuf[(b*32768+sp)*128 + c]
// + per-token LN stats (mu, rstd) for the layer-0 fused-LN QKV GEMM.
// ---------------------------------------------------------------------------
__global__ __launch_bounds__(256) void transpose_in_kernel(
    const float* __restrict__ x, float* __restrict__ out, float* __restrict__ tstats)
{
    __shared__ float tile[128 * 65];
    int chunk = blockIdx.x;
    int tid = threadIdx.x;
    int b = chunk >> 9;
    int sp0 = (chunk & 511) * 64;
    #pragma unroll
    for (int l = 0; l < 32; ++l) {
        int idx = l * 256 + tid;
        int c = idx >> 6;
        int s = idx & 63;
        tile[c * 65 + s] = x[(((size_t)(b * 128 + c)) << 15) + sp0 + s];
    }
    __syncthreads();
    #pragma unroll
    for (int l = 0; l < 32; ++l) {
        int idx = l * 256 + tid;
        int s = idx >> 7;
        int c = idx & 127;
        out[((size_t)((b << 15) + sp0 + s)) * 128 + c] = tile[c * 65 + s];
    }
    // per-token LN stats: 4 threads per token, 32 channels each
    int s = tid >> 2, q = tid & 3;
    float sm = 0.f, sq = 0.f;
    #pragma unroll
    for (int cc = 0; cc < 32; ++cc) {
        float v = tile[(q * 32 + cc) * 65 + s];
        sm += v; sq += v * v;
    }
    sm += __shfl_xor(sm, 1); sq += __shfl_xor(sq, 1);
    sm += __shfl_xor(sm, 2); sq += __shfl_xor(sq, 2);
    if (q == 0) {
        float mu = sm * (1.0f / 128.0f);
        float var = sq * (1.0f / 128.0f) - mu * mu;
        size_t tok = (size_t)(b << 15) + sp0 + s;
        tstats[tok * 2]     = mu;
        tstats[tok * 2 + 1] = rsqrtf(var + 1e-5f);
    }
}

// ---------------------------------------------------------------------------
// Prep: weight fp32->bf16 conversions + dw-weight transpose + stats zero.
// qkv weights are LN1-gamma-folded. proj weights are packed into MFMA
// B-fragment order for the fused proj+MLP kernel:
//   idx bits wv(2)|ks(2)|nt(1)|lane(6)|j(3) ->
//   proj_w[n = wv*32+nt*16+(lane&15)][k = ks*32+(lane>>4)*8+j]
// ---------------------------------------------------------------------------
__global__ __launch_bounds__(256) void prep_kernel(
    const float* __restrict__ qkv_w, const float* __restrict__ proj_w,
    const float* __restrict__ fc1_w, const float* __restrict__ fc2_w,
    const float* __restrict__ pw_w, const float* __restrict__ dw_w,
    const float* __restrict__ norm1_g,
    bf16* __restrict__ wbf, float* __restrict__ dwt, float* __restrict__ stats)
{
    int i = blockIdx.x * 256 + threadIdx.x;
    float v;
    if (i < 196608) {
        int layer = i / 49152, k = i & 127;
        v = qkv_w[i] * norm1_g[layer * 128 + k];
    }
    else if (i < 262144) {
        int jd = i - 196608;
        int layer = jd >> 14, idx = jd & 16383;
        int j = idx & 7, lane = (idx >> 3) & 63;
        int nt = (idx >> 9) & 1, ks = (idx >> 10) & 3, wvv = (idx >> 12) & 3;
        int row = wvv * 32 + nt * 16 + (lane & 15);
        int col = ks * 32 + (lane >> 4) * 8 + j;
        v = proj_w[layer * 16384 + row * 128 + col];
    }
    else if (i < 524288)  v = fc1_w[i - 262144];
    else if (i < 786432)  v = fc2_w[i - 524288];
    else                  v = pw_w[i - 786432];
    wbf[i] = __float2bfloat16(v);
    if (i < 3456) {
        int c = i / 27, k = i % 27;
        dwt[k * 128 + c] = dw_w[i];
    }
    if (i < 512) stats[i] = 0.f;
}

// ---------------------------------------------------------------------------
// Fold LN betas into biases:
//  fb[0..1536)  : qkvb[l][n]  = qkv_b + sum_k qkv_w[l][n][k]*norm1_b[l][k]
//  fb[1536..3584): b1f[l][n]  = fc1_b + sum_k fc1_w[l][n][k]*norm2_b[l][k]
// ---------------------------------------------------------------------------
__global__ __launch_bounds__(256) void foldbias_kernel(
    const float* __restrict__ qkv_w, const float* __restrict__ qkv_b,
    const float* __restrict__ norm1_b,
    const float* __restrict__ fc1_w, const float* __restrict__ fc1_b,
    const float* __restrict__ norm2_b, float* __restrict__ fb)
{
    int t = blockIdx.x * 256 + threadIdx.x;
    if (t < 1536) {
        int l = t / 384, n = t % 384;
        const float* wr = qkv_w + (size_t)l * 49152 + n * 128;
        const float* br = norm1_b + l * 128;
        float s = qkv_b[t];
        #pragma unroll 4
        for (int k = 0; k < 128; ++k) s += wr[k] * br[k];
        fb[t] = s;
    } else if (t < 3584) {
        int u = t - 1536;
        int l = u >> 9, n = u & 511;
        const float* wr = fc1_w + (size_t)l * 65536 + n * 128;
        const float* br = norm2_b + l * 128;
        float s = fc1_b[l * 512 + n];
        #pragma unroll 4
        for (int k = 0; k < 128; ++k) s += wr[k] * br[k];
        fb[t] = s;
    }
}

// ---------------------------------------------------------------------------
// Pack fc1/fc2 weights into MFMA-fragment order for the 4-chunk MLP.
// pw1 is LN2-gamma-folded (gamma indexes the k dimension = col).
// pw1 flat idx bits: cc(2)|wv(2)|kk(2)|nt(1)|lane(6)|j(3) ->
//   fc1_w[row = cc*128 + wv*32 + nt*16 + (lane&15)][col = kk*32 + (lane>>4)*8 + j]
// pw2 flat idx bits: wv(2)|cc(2)|ks(2)|nt(1)|lane(6)|j(3) ->
//   fc2_w[row = wv*32 + nt*16 + (lane&15)][col = cc*128 + ks*32 + (lane>>4)*8 + j]
// ---------------------------------------------------------------------------
__global__ __launch_bounds__(256) void pack_kernel(
    const float* __restrict__ fc1_w, const float* __restrict__ fc2_w,
    const float* __restrict__ norm2_g,
    bf16* __restrict__ pw1, bf16* __restrict__ pw2)
{
    int t = blockIdx.x * 256 + threadIdx.x;
    int i = t >> 17;
    int rem = t & 131071;
    int type = rem >> 16;
    int idx = rem & 65535;
    int j = idx & 7, lane = (idx >> 3) & 63;
    int ln15 = lane & 15, quad = lane >> 4;
    if (type == 0) {
        int nt = (idx >> 9) & 1, kk = (idx >> 10) & 3, wv = (idx >> 12) & 3, cc = (idx >> 14) & 3;
        int row = cc * 128 + wv * 32 + nt * 16 + ln15;
        int col = kk * 32 + quad * 8 + j;
        pw1[i * 65536 + idx] = __float2bfloat16(
            fc1_w[(size_t)i * 65536 + row * 128 + col] * norm2_g[i * 128 + col]);
    } else {
        int nt = (idx >> 9) & 1, ks = (idx >> 10) & 3, cc = (idx >> 12) & 3, wv = (idx >> 14) & 3;
        int row = wv * 32 + nt * 16 + ln15;
        int col = cc * 128 + ks * 32 + quad * 8 + j;
        pw2[i * 65536 + idx] = __float2bfloat16(fc2_w[(size_t)i * 65536 + row * 512 + col]);
    }
}

// ---------------------------------------------------------------------------
// Expand relative-position bias + shift mask into rpe[wtype][head][64][64] f32.
// ---------------------------------------------------------------------------
__global__ __launch_bounds__(256) void rpe_expand_kernel(
    const float* __restrict__ rpb, float* __restrict__ rpe, int layer)
{
    int t = blockIdx.x * 256 + threadIdx.x;
    int j = t & 63, i = (t >> 6) & 63, head = (t >> 12) & 7, wt = t >> 15;
    int ih = i >> 4, iw = (i >> 2) & 3, it = i & 3;
    int jh = j >> 4, jw = (j >> 2) & 3, jt = j & 3;
    int ridx = ((ih - jh + 3) * 7 + (iw - jw + 3)) * 7 + (it - jt + 3);
    float v = rpb[layer * 2744 + ridx * 8 + head];
    if (wt) {
        bool ok = true;
        if (wt & 4) ok = ok && ((ih >= 2) == (jh >= 2));
        if (wt & 2) ok = ok && ((iw >= 2) == (jw >= 2));
        if (wt & 1) ok = ok && ((it >= 2) == (jt >= 2));
        if (!ok) v -= 100.f;
    }
    rpe[t] = v;
}

// ---------------------------------------------------------------------------
// bf16 MFMA GEMM with coalesced LDS-staged epilogues.
// mode 0 (QKV): A-staging gathers fp32 rows from xbuf (Cf) with the shift-
// window token map and applies bf16((x-mu)*rstd) — gamma/beta folded into
// weights/bias. q columns (nBase==0) pre-scaled 0.25 in epilogue.
// mode 4/5: pointwise-conv stats / BN+ReLU epilogues (connectBlock).
// ---------------------------------------------------------------------------
__global__ __launch_bounds__(256) void gemm_bf16_kernel(
    const bf16* __restrict__ A, const bf16* __restrict__ Bw,
    const float* __restrict__ bias, bf16* __restrict__ Cb, float* __restrict__ Cf,
    float* __restrict__ aux, const float* __restrict__ p1, const float* __restrict__ p2,
    int M, int N, int K, int mode, int shift)
{
    __shared__ __align__(16) char smem[34816];
    __shared__ float cs[128];
    __shared__ float cq[128];
    short* As = (short*)smem;
    short* Bs = (short*)(smem + 8192);
    int tid = threadIdx.x;
    int lane = tid & 63, wv = tid >> 6;
    int wm = wv >> 1, wn = wv & 1;
    int ln15 = lane & 15, quad = lane >> 4;
    int q8 = quad * 8;
    int nBase = blockIdx.x * 128;
    int mBase = blockIdx.y * 128;
    floatx4 acc[4][4] = {};

    if (mode == 4 && tid < 128) { cs[tid] = 0.f; cq[tid] = 0.f; }

    int srow = tid >> 2, scb = tid & 3;

    int toks[2]; float tmu[2], trs[2];
    if (mode == 0) {
        #pragma unroll
        for (int i = 0; i < 2; ++i) {
            int m = mBase + srow + i * 64;
            int n = m & 63, w = (m >> 6) & 511, b = m >> 15;
            int ih = n >> 4, iw = (n >> 2) & 3, it = n & 3;
            int wh = w >> 6, ww = (w >> 3) & 7, wt = w & 7;
            int h  = (wh * 4 + ih + shift) & 31;
            int w2 = (ww * 4 + iw + shift) & 31;
            int t  = (wt * 4 + it + shift) & 31;
            toks[i] = (b << 15) + ((h * 32 + w2) * 32 + t);
            tmu[i] = aux[(size_t)toks[i] * 2];
            trs[i] = aux[(size_t)toks[i] * 2 + 1];
        }
    }

    for (int k0 = 0; k0 < K; k0 += 32) {
        if (mode == 0) {
            int cb = k0 + scb * 8;
            #pragma unroll
            for (int i = 0; i < 2; ++i) {
                const float* xr = Cf + (size_t)toks[i] * 128 + cb;
                float4 a0 = *(const float4*)xr;
                float4 a1 = *(const float4*)(xr + 4);
                float mu = tmu[i], rs = trs[i];
                __align__(16) bf16 pk[8];
                pk[0] = __float2bfloat16((a0.x - mu) * rs);
                pk[1] = __float2bfloat16((a0.y - mu) * rs);
                pk[2] = __float2bfloat16((a0.z - mu) * rs);
                pk[3] = __float2bfloat16((a0.w - mu) * rs);
                pk[4] = __float2bfloat16((a1.x - mu) * rs);
                pk[5] = __float2bfloat16((a1.y - mu) * rs);
                pk[6] = __float2bfloat16((a1.z - mu) * rs);
                pk[7] = __float2bfloat16((a1.w - mu) * rs);
                ((uint4*)As)[i * 256 + tid] = *(const uint4*)pk;
                ((uint4*)Bs)[i * 256 + tid] =
                    *(const uint4*)(Bw + (size_t)(nBase + srow + i * 64) * K + cb);
            }
        } else {
            #pragma unroll
            for (int i = 0; i < 2; ++i) {
                int row = srow + i * 64;
                ((uint4*)As)[i * 256 + tid] =
                    *(const uint4*)(A + (size_t)(mBase + row) * K + k0 + scb * 8);
                ((uint4*)Bs)[i * 256 + tid] =
                    *(const uint4*)(Bw + (size_t)(nBase + row) * K + k0 + scb * 8);
            }
        }
        __syncthreads();
        short8 af[4], bfr[4];
        #pragma unroll
        for (int mt = 0; mt < 4; ++mt)
            af[mt] = *(const short8*)&As[(wm * 64 + mt * 16 + ln15) * 32 + q8];
        #pragma unroll
        for (int nt = 0; nt < 4; ++nt)
            bfr[nt] = *(const short8*)&Bs[(wn * 64 + nt * 16 + ln15) * 32 + q8];
        #pragma unroll
        for (int mt = 0; mt < 4; ++mt)
            #pragma unroll
            for (int nt = 0; nt < 4; ++nt)
                acc[mt][nt] = __builtin_amdgcn_mfma_f32_16x16x32_bf16(
                    af[mt], bfr[nt], acc[mt][nt], 0, 0, 0);
        __syncthreads();
    }

    if (mode == 4) {
        #pragma unroll
        for (int nt = 0; nt < 4; ++nt) {
            int nl = wn * 64 + nt * 16 + ln15;
            float bs = bias[nBase + nl];
            float s = 0.f, sq = 0.f;
            #pragma unroll
            for (int mt = 0; mt < 4; ++mt)
                #pragma unroll
                for (int r = 0; r < 4; ++r) {
                    float v = acc[mt][nt][r] + bs;
                    s += v; sq += v * v;
                }
            atomicAdd(&cs[nl], s);
            atomicAdd(&cq[nl], sq);
        }
        __syncthreads();
        if (tid < 128) {
            atomicAdd(&aux[nBase + tid], cs[tid]);
            atomicAdd(&aux[256 + nBase + tid], cq[tid]);
        }
        return;
    }

    if (mode == 0) {
        bf16* estage = (bf16*)smem;          // [128][136]
        float qsc = (nBase == 0) ? 0.25f : 1.0f;
        #pragma unroll
        for (int mt = 0; mt < 4; ++mt)
            #pragma unroll
            for (int nt = 0; nt < 4; ++nt)
                #pragma unroll
                for (int r = 0; r < 4; ++r) {
                    int row = wm * 64 + mt * 16 + quad * 4 + r;
                    int col = wn * 64 + nt * 16 + ln15;
                    estage[row * 136 + col] =
                        __float2bfloat16((acc[mt][nt][r] + bias[nBase + col]) * qsc);
                }
        __syncthreads();
        int row = tid >> 1, hf = tid & 1;
        #pragma unroll
        for (int j = 0; j < 4; ++j) {
            int col = hf * 64 + j * 16;
            *(uint4*)(Cb + (size_t)(mBase + row) * N + nBase + col) =
                *(const uint4*)&estage[row * 136 + col];
            *(uint4*)(Cb + (size_t)(mBase + row) * N + nBase + col + 8) =
                *(const uint4*)&estage[row * 136 + col + 8];
        }
        return;
    }

    // mode 5: BN + ReLU + transposed store
    {
        float* fstage = (float*)smem;        // [64 nn][132 sp]
        int b = mBase >> 15, sp0 = mBase & 32767;
        #pragma unroll
        for (int hf = 0; hf < 2; ++hf) {
            if (wn == hf) {
                #pragma unroll
                for (int nt = 0; nt < 4; ++nt) {
                    int ncol = nt * 16 + ln15;
                    int nn = nBase + hf * 64 + ncol;
                    float mean = aux[nn] * (1.0f / 65536.0f);
                    float var  = aux[256 + nn] * (1.0f / 65536.0f) - mean * mean;
                    float sc = rsqrtf(var + 1e-5f) * p1[nn];
                    float off = p2[nn] + bias[nn] * sc - mean * sc;
                    #pragma unroll
                    for (int mt = 0; mt < 4; ++mt)
                        #pragma unroll
                        for (int r = 0; r < 4; ++r) {
                            int ml = wm * 64 + mt * 16 + quad * 4 + r;
                            float y = acc[mt][nt][r] * sc + off;
                            fstage[ncol * 132 + ml] = fmaxf(y, 0.f);
                        }
                }
            }
            __syncthreads();
            int nl = tid >> 2, part = tid & 3;
            int nn = nBase + hf * 64 + nl;
            float* dst = Cf + (((size_t)(b * 256 + nn)) << 15) + sp0 + part * 32;
            #pragma unroll
            for (int j = 0; j < 8; ++j)
                *(float4*)(dst + j * 4) = *(const float4*)&fstage[nl * 132 + part * 32 + j * 4];
            __syncthreads();
        }
    }
}

// ---------------------------------------------------------------------------
// Fused proj + residual + LN2 + MLP (v7.3). Each block = 64 natural-order
// tokens; x_mid round-tripped through xbuf. amdgpu_waves_per_eu(4,4) pins
// the occupancy range: launch_bounds' min-only bound let the allocator
// target 8 waves/EU (64 VGPR) and spill 30-50 MB/dispatch to scratch
// (R8-R10). Pinning min=max=4 gives a 128-VGPR budget with no incentive to
// shrink; live set ~108 VGPR -> spill-free. Steps 3+4 fused: the shfl
// butterfly leaves (mu,rs) in every lane, so the LN2'd aln write happens in
// the same pass as the x_mid writeback (no tmr, one less barrier + read).
// ---------------------------------------------------------------------------
__global__ __launch_bounds__(256)
__attribute__((amdgpu_waves_per_eu(4, 4)))
void mlp_kernel(
    float* __restrict__ xbuf, const bf16* __restrict__ attnbuf,
    const bf16* __restrict__ ppw, const float* __restrict__ pb,
    const bf16* __restrict__ pw1, const float* __restrict__ b1,
    const bf16* __restrict__ pw2, const float* __restrict__ b2,
    bf16* __restrict__ xout16, float* __restrict__ tstats, int shift)
{
    __shared__ __align__(16) bf16 smem[64 * 136 * 2];   // 34 KB
    bf16* aln  = smem;              // [64][136] atile / LN2'd x_mid
    bf16* hidc = smem + 64 * 136;   // [64][136] per-chunk hidden
    float* ostage = (float*)smem;   // [64][132] f32, full-smem alias
    int tid = threadIdx.x;
    int lane = tid & 63, wv = tid >> 6;
    int ln15 = lane & 15, quad = lane >> 4;
    int q8 = quad * 8;
    int blk = blockIdx.x;
    size_t tok0 = (size_t)blk * 64;
    int b = blk >> 9, h = (blk >> 4) & 31, wpair = blk & 15;

    // 1. gather attnbuf (window order) -> atile rows in natural-local order
    #pragma unroll
    for (int l = 0; l < 4; ++l) {
        int q = l * 256 + tid;
        int row = q >> 4, c16 = q & 15;
        int w2 = wpair * 2 + (row >> 5), t = row & 31;
        int hs = (h - shift) & 31, ws = (w2 - shift) & 31, ts = (t - shift) & 31;
        int wr = (b << 15) + (((hs >> 2) * 64 + ((ws >> 2) << 3) + (ts >> 2)) << 6)
               + ((hs & 3) * 16 + ((ws & 3) << 2) + (ts & 3));
        *(uint4*)&aln[row * 136 + c16 * 8] =
            *(const uint4*)((const short*)attnbuf + (size_t)wr * 128 + c16 * 8);
    }
    __syncthreads();

    // 2. proj: out[64][128]; wave wv -> cols wv*32..+31, K=128
    floatx4 accp[4][2] = {};
    #pragma unroll
    for (int ks = 0; ks < 4; ++ks) {
        short8 af[4], bfr[2];
        #pragma unroll
        for (int mt = 0; mt < 4; ++mt)
            af[mt] = *(const short8*)&aln[(mt * 16 + ln15) * 136 + ks * 32 + q8];
        #pragma unroll
        for (int nt = 0; nt < 2; ++nt)
            bfr[nt] = *(const short8*)(ppw + wv * 4096 + ks * 1024 + nt * 512 + lane * 8);
        #pragma unroll
        for (int mt = 0; mt < 4; ++mt)
            #pragma unroll
            for (int nt = 0; nt < 2; ++nt)
                accp[mt][nt] = __builtin_amdgcn_mfma_f32_16x16x32_bf16(
                    af[mt], bfr[nt], accp[mt][nt], 0, 0, 0);
    }
    __syncthreads();   // atile dead -> ostage (full smem)

    #pragma unroll
    for (int mt = 0; mt < 4; ++mt)
        #pragma unroll
        for (int nt = 0; nt < 2; ++nt)
            #pragma unroll
            for (int r = 0; r < 4; ++r) {
                int m = mt * 16 + quad * 4 + r;
                int n = wv * 32 + nt * 16 + ln15;
                ostage[m * 132 + n] = accp[mt][nt][r] + pb[n];
            }
    __syncthreads();

    // 3+4. x_mid = xbuf + proj -> xbuf; LN2 (folded) -> aln bf16, one pass.
    // NOTE: ostage and aln alias; ostage row t lives at bytes [t*528, +528)
    // while aln row t is [t*272, +272) — all aln rows for the 8 tokens of
    // iteration jj precede their ostage rows only for low t, so we must
    // buffer the 8 ostage values in regs BEFORE writing aln. Each thread
    // only touches its own (t,c) in both arrays; within the iteration we
    // read ostage first, then write aln after a wave-local ordering is NOT
    // enough (other waves read different rows) — but each (t,c) cell of
    // aln is written by the same thread that read ostage(t,c'), and aln
    // writes land in bytes belonging to rows <64 of ostage that other
    // threads may still read this iteration. To stay safe, split with one
    // barrier: read+residual+stats first into regs (per-iteration), then
    // write aln after the barrier.
    float4 vsave[8];
    float musave[8], rssave[8];
    #pragma unroll
    for (int jj = 0; jj < 8; ++jj) {
        int idx = (jj * 256 + tid) * 4;
        int t = idx >> 7, c = idx & 127;
        float4 v = *(const float4*)(xbuf + tok0 * 128 + idx);
        float4 o = *(const float4*)&ostage[t * 132 + c];
        v.x += o.x; v.y += o.y; v.z += o.z; v.w += o.w;
        *(float4*)(xbuf + tok0 * 128 + idx) = v;
        float ps = v.x + v.y + v.z + v.w;
        float pq = v.x * v.x + v.y * v.y + v.z * v.z + v.w * v.w;
        #pragma unroll
        for (int o2 = 16; o2 > 0; o2 >>= 1) {
            ps += __shfl_xor(ps, o2); pq += __shfl_xor(pq, o2);
        }
        float mu = ps * (1.0f / 128.0f);
        float var = pq * (1.0f / 128.0f) - mu * mu;
        vsave[jj] = v;
        musave[jj] = mu;
        rssave[jj] = rsqrtf(var + 1e-5f);
    }
    __syncthreads();   // all ostage reads done -> aln region reusable
    #pragma unroll
    for (int jj = 0; jj < 8; ++jj) {
        int idx = (jj * 256 + tid) * 4;
        int t = idx >> 7, c = idx & 127;
        float4 v = vsave[jj];
        float mu = musave[jj], rs = rssave[jj];
        __align__(8) bf16 hh[4];
        hh[0] = __float2bfloat16((v.x - mu) * rs);
        hh[1] = __float2bfloat16((v.y - mu) * rs);
        hh[2] = __float2bfloat16((v.z - mu) * rs);
        hh[3] = __float2bfloat16((v.w - mu) * rs);
        *(uint2*)&aln[t * 136 + c] = *(const uint2*)hh;
    }
    __syncthreads();

    // 5. 4-chunk MLP (R5-proven)
    floatx4 acc2[4][2] = {};
    #pragma unroll
    for (int cc = 0; cc < 4; ++cc) {
        floatx4 acc[4][2] = {};
        const bf16* p1w = pw1 + (size_t)(cc * 4 + wv) * 4096;
        #pragma unroll
        for (int kk = 0; kk < 4; ++kk) {
            short8 af[4], bfr[2];
            #pragma unroll
            for (int mt = 0; mt < 4; ++mt)
                af[mt] = *(const short8*)&aln[(mt * 16 + ln15) * 136 + kk * 32 + q8];
            #pragma unroll
            for (int nt = 0; nt < 2; ++nt)
                bfr[nt] = *(const short8*)(p1w + kk * 1024 + nt * 512 + lane * 8);
            #pragma unroll
            for (int mt = 0; mt < 4; ++mt)
                #pragma unroll
                for (int nt = 0; nt < 2; ++nt)
                    acc[mt][nt] = __builtin_amdgcn_mfma_f32_16x16x32_bf16(
                        af[mt], bfr[nt], acc[mt][nt], 0, 0, 0);
        }
        if (cc) __syncthreads();
        #pragma unroll
        for (int mt = 0; mt < 4; ++mt)
            #pragma unroll
            for (int nt = 0; nt < 2; ++nt)
                #pragma unroll
                for (int r = 0; r < 4; ++r) {
                    int m = mt * 16 + quad * 4 + r;
                    int ncl = wv * 32 + nt * 16 + ln15;
                    float v = acc[mt][nt][r] + b1[cc * 128 + ncl];
                    float u = v * (0.7978845608f + 0.0356774081f * v * v);
                    v = v * __builtin_amdgcn_rcpf(1.f + __expf(-2.f * u));
                    hidc[m * 136 + ncl] = __float2bfloat16(v);
                }
        __syncthreads();
        const bf16* p2w = pw2 + (size_t)(wv * 4 + cc) * 4096;
        #pragma unroll
        for (int ks = 0; ks < 4; ++ks) {
            short8 af[4], bfr[2];
            #pragma unroll
            for (int mt = 0; mt < 4; ++mt)
                af[mt] = *(const short8*)&hidc[(mt * 16 + ln15) * 136 + ks * 32 + q8];
            #pragma unroll
            for (int nt = 0; nt < 2; ++nt)
                bfr[nt] = *(const short8*)(p2w + ks * 1024 + nt * 512 + lane * 8);
            #pragma unroll
            for (int mt = 0; mt < 4; ++mt)
                #pragma unroll
                for (int nt = 0; nt < 2; ++nt)
                    acc2[mt][nt] = __builtin_amdgcn_mfma_f32_16x16x32_bf16(
                        af[mt], bfr[nt], acc2[mt][nt], 0, 0, 0);
        }
    }
    __syncthreads();   // aln/hidc dead -> ostage2 (full smem)

    #pragma unroll
    for (int mt = 0; mt < 4; ++mt)
        #pragma unroll
        for (int nt = 0; nt < 2; ++nt)
            #pragma unroll
            for (int r = 0; r < 4; ++r) {
                int m = mt * 16 + quad * 4 + r;
                int n = wv * 32 + nt * 16 + ln15;
                ostage[m * 132 + n] = acc2[mt][nt][r] + b2[n];
            }
    __syncthreads();

    // 6. final residual: re-read own x_mid lines + MLP out; next-layer stats
    #pragma unroll
    for (int jj = 0; jj < 8; ++jj) {
        int idx = (jj * 256 + tid) * 4;
        int t = idx >> 7, c = idx & 127;
        float4 v = *(const float4*)(xbuf + tok0 * 128 + idx);
        float4 o = *(const float4*)&ostage[t * 132 + c];
        v.x += o.x; v.y += o.y; v.z += o.z; v.w += o.w;
        *(float4*)(xbuf + tok0 * 128 + idx) = v;
        if (xout16) {
            __align__(8) bf16 hh[4];
            hh[0] = __float2bfloat16(v.x); hh[1] = __float2bfloat16(v.y);
            hh[2] = __float2bfloat16(v.z); hh[3] = __float2bfloat16(v.w);
            *(uint2*)(xout16 + tok0 * 128 + idx) = *(const uint2*)hh;
        }
        float ps = v.x + v.y + v.z + v.w;
        float pq = v.x * v.x + v.y * v.y + v.z * v.z + v.w * v.w;
        #pragma unroll
        for (int o2 = 16; o2 > 0; o2 >>= 1) {
            ps += __shfl_xor(ps, o2); pq += __shfl_xor(pq, o2);
        }
        if ((tid & 31) == 0) {
            float mu = ps * (1.0f / 128.0f);
            float var = pq * (1.0f / 128.0f) - mu * mu;
            size_t tok = tok0 + t;
            tstats[tok * 2]     = mu;
            tstats[tok * 2 + 1] = rsqrtf(var + 1e-5f);
        }
    }
}

// ---------------------------------------------------------------------------
// MFMA windowed attention (unchanged).
// ---------------------------------------------------------------------------
__global__ __launch_bounds__(256, 3) void attn_mfma_kernel(
    const bf16* __restrict__ qkv, const float* __restrict__ rpe,
    bf16* __restrict__ outp, int shift)
{
    __shared__ __align__(16) short qs[64 * 392];   // 49 KB; reused as O stage
    int tid = threadIdx.x;
    int lane = tid & 63, wv = tid >> 6;
    int ln15 = lane & 15, quad = lane >> 4;
    int win = blockIdx.x;
    size_t tok0 = (size_t)win * 64;

    const short* gq = (const short*)qkv + tok0 * 384;
    #pragma unroll
    for (int l = 0; l < 12; ++l) {
        int idx = l * 256 + tid;
        int r = idx / 48, c = idx - r * 48;
        *(uint4*)&qs[r * 392 + c * 8] = *(const uint4*)&gq[r * 384 + c * 8];
    }
    int w = win & 511;
    int wtype = 0;
    if (shift)
        wtype = (((w >> 6) == 7) << 2) | ((((w >> 3) & 7) == 7) << 1) | (int)((w & 7) == 7);
    const float* rpw = rpe + ((size_t)(wtype * 8) << 12);
    __syncthreads();

    floatx4 oacc[2][4];
    #pragma unroll
    for (int hh = 0; hh < 2; ++hh) {
        int head = wv * 2 + hh;
        const float* rph = rpw + ((size_t)head << 12);

        floatx4 acc[4][4];
        #pragma unroll
        for (int jt = 0; jt < 4; ++jt)
            #pragma unroll
            for (int it = 0; it < 4; ++it)
                acc[jt][it] = *(const floatx4*)&rph[(it * 16 + ln15) * 64 + jt * 16 + quad * 4];

        short4v qf[4], kf[4];
        #pragma unroll
        for (int it = 0; it < 4; ++it)
            qf[it] = *(const short4v*)&qs[(it * 16 + ln15) * 392 + head * 16 + quad * 4];
        #pragma unroll
        for (int jt = 0; jt < 4; ++jt)
            kf[jt] = *(const short4v*)&qs[(jt * 16 + ln15) * 392 + 128 + head * 16 + quad * 4];

        #pragma unroll
        for (int jt = 0; jt < 4; ++jt)
            #pragma unroll
            for (int it = 0; it < 4; ++it)
                acc[jt][it] = mfma16(kf[jt], qf[it], acc[jt][it]);

        short4v pf[4][4];
        #pragma unroll
        for (int it = 0; it < 4; ++it) {
            float m = -1e30f;
            #pragma unroll
            for (int jt = 0; jt < 4; ++jt)
                #pragma unroll
                for (int r = 0; r < 4; ++r) m = fmaxf(m, acc[jt][it][r]);
            m = fmaxf(m, __shfl_xor(m, 16));
            m = fmaxf(m, __shfl_xor(m, 32));
            float s = 0.f;
            #pragma unroll
            for (int jt = 0; jt < 4; ++jt)
                #pragma unroll
                for (int r = 0; r < 4; ++r) {
                    float e = __expf(acc[jt][it][r] - m);
                    acc[jt][it][r] = e; s += e;
                }
            s += __shfl_xor(s, 16);
            s += __shfl_xor(s, 32);
            float inv = 1.0f / s;
            #pragma unroll
            for (int jt = 0; jt < 4; ++jt) {
                __align__(8) bf16 pb[4];
                #pragma unroll
                for (int r = 0; r < 4; ++r)
                    pb[r] = __float2bfloat16(acc[jt][it][r] * inv);
                pf[jt][it] = *(const short4v*)pb;
            }
        }

        short4v vf[4];
        #pragma unroll
        for (int jt = 0; jt < 4; ++jt)
            #pragma unroll
            for (int jj = 0; jj < 4; ++jj)
                vf[jt][jj] = qs[(jt * 16 + quad * 4 + jj) * 392 + 256 + head * 16 + ln15];

        #pragma unroll
        for (int it = 0; it < 4; ++it) {
            floatx4 o = {0.f, 0.f, 0.f, 0.f};
            #pragma unroll
            for (int jt = 0; jt < 4; ++jt)
                o = mfma16(vf[jt], pf[jt][it], o);
            oacc[hh][it] = o;
        }
    }
    __syncthreads();   // all qs reads done -> reuse as O stage [64][136]

    short* ob = qs;
    #pragma unroll
    for (int hh = 0; hh < 2; ++hh)
        #pragma unroll
        for (int it = 0; it < 4; ++it) {
            __align__(8) bf16 t4[4];
            #pragma unroll
            for (int r = 0; r < 4; ++r) t4[r] = __float2bfloat16(oacc[hh][it][r]);
            *(short4v*)&ob[(it * 16 + ln15) * 136 + (wv * 2 + hh) * 16 + quad * 4] =
                *(const short4v*)t4;
        }
    __syncthreads();

    short* po = (short*)outp + tok0 * 128;
    #pragma unroll
    for (int l = 0; l < 4; ++l) {
        int idx = l * 256 + tid;
        int r = idx >> 4, c = idx & 15;
        *(uint4*)&po[r * 128 + c * 8] = *(const uint4*)&ob[r * 136 + c * 8];
    }
}

// ---------------------------------------------------------------------------
// Depthwise 3x3x3 conv v2 (unchanged).
// ---------------------------------------------------------------------------
__global__ __launch_bounds__(256) void dwconv_kernel(
    const bf16* __restrict__ x, const float* __restrict__ dwt,
    const float* __restrict__ bias, bf16* __restrict__ out)
{
    int blk = blockIdx.x;                  // b(1) | h(5) | wpair(4)
    int b = blk >> 9;
    int h = (blk >> 4) & 31;
    int w = ((blk & 15) << 1) | (threadIdx.x >> 7);
    int tid = threadIdx.x & 127;
    int c0 = (tid & 31) * 4;
    int t0 = (tid >> 5) * 8;

    float4 acc[8];
    float4 bs = *(const float4*)&bias[c0];
    #pragma unroll
    for (int o = 0; o < 8; ++o) acc[o] = bs;

    #pragma unroll
    for (int kh = 0; kh < 3; ++kh) {
        int hh = h + kh - 1;
        if (hh < 0 || hh > 31) continue;
        #pragma unroll
        for (int kw = 0; kw < 3; ++kw) {
            int ww = w + kw - 1;
            if (ww < 0 || ww > 31) continue;
            const short* px = (const short*)x +
                ((size_t)(b << 15) + (hh * 32 + ww) * 32) * 128 + c0;
            float4 v[10];
            #pragma unroll
            for (int u = 0; u < 10; ++u) {
                int tt = t0 - 1 + u;
                if (tt >= 0 && tt < 32) {
                    short4v s4 = *(const short4v*)(px + (size_t)tt * 128);
                    v[u].x = b2f(s4[0]); v[u].y = b2f(s4[1]);
                    v[u].z = b2f(s4[2]); v[u].w = b2f(s4[3]);
                } else {
                    v[u].x = v[u].y = v[u].z = v[u].w = 0.f;
                }
            }
            int kb = kh * 9 + kw * 3;
            float4 w0 = *(const float4*)&dwt[(kb + 0) * 128 + c0];
            float4 w1 = *(const float4*)&dwt[(kb + 1) * 128 + c0];
            float4 w2 = *(const float4*)&dwt[(kb + 2) * 128 + c0];
            #pragma unroll
            for (int o = 0; o < 8; ++o) {
                acc[o].x += v[o].x * w0.x + v[o + 1].x * w1.x + v[o + 2].x * w2.x;
                acc[o].y += v[o].y * w0.y + v[o + 1].y * w1.y + v[o + 2].y * w2.y;
                acc[o].z += v[o].z * w0.z + v[o + 1].z * w1.z + v[o + 2].z * w2.z;
                acc[o].w += v[o].w * w0.w + v[o + 1].w * w1.w + v[o + 2].w * w2.w;
            }
        }
    }
    short* po = (short*)out + ((size_t)(b << 15) + (h * 32 + w) * 32 + t0) * 128 + c0;
    #pragma unroll
    for (int o = 0; o < 8; ++o) {
        __align__(8) bf16 h4[4];
        h4[0] = __float2bfloat16(acc[o].x);
        h4[1] = __float2bfloat16(acc[o].y);
        h4[2] = __float2bfloat16(acc[o].z);
        h4[3] = __float2bfloat16(acc[o].w);
        *(uint2*)(po + (size_t)o * 128) = *(const uint2*)h4;
    }
}

// ---------------------------------------------------------------------------
extern "C" void kernel_launch(void* const* d_in, const int* in_sizes, int n_in,
                              void* d_out, int out_size, void* d_ws, size_t ws_size,
                              hipStream_t stream)
{
    const float* x_in    = (const float*)d_in[0];
    const float* norm1_g = (const float*)d_in[1];
    const float* norm1_b = (const float*)d_in[2];
    const float* qkv_w   = (const float*)d_in[3];
    const float* qkv_b   = (const float*)d_in[4];
    const float* proj_w  = (const float*)d_in[5];
    const float* proj_b  = (const float*)d_in[6];
    const float* rpb     = (const float*)d_in[7];
    const float* norm2_g = (const float*)d_in[8];
    const float* norm2_b = (const float*)d_in[9];
    const float* fc1_w   = (const float*)d_in[10];
    const float* fc1_b   = (const float*)d_in[11];
    const float* fc2_w   = (const float*)d_in[12];
    const float* fc2_b   = (const float*)d_in[13];
    const float* dw_w    = (const float*)d_in[14];
    const float* dw_b    = (const float*)d_in[15];
    const float* pw_w    = (const float*)d_in[16];
    const float* pw_b    = (const float*)d_in[17];
    const float* bn_g    = (const float*)d_in[18];
    const float* bn_b    = (const float*)d_in[19];
    float* out = (float*)d_out;

    char* ws = (char*)d_ws;
    float* xbuf   = (float*)ws;                          // [0,32MB)   fp32 [TOK,128]
    bf16*  wbf    = (bf16*)(ws + 33554432ULL);           // [32,34MB)  bf16 weights
    float* dwt    = (float*)(ws + 35651584ULL);          // 27x128 fp32
    float* stats  = (float*)(ws + 35717120ULL);          // 2 KB
    float* fb     = (float*)(ws + 35719168ULL);          // 14 KB folded biases
    bf16*  pw1    = (bf16*)(ws + 35782656ULL);           // 512 KB packed fc1
    bf16*  pw2    = (bf16*)(ws + 36306944ULL);           // 512 KB packed fc2
    float* tstats = (float*)(ws + 36831232ULL);          // 512 KB per-token LN stats
    bf16*  lnbuf  = (bf16*)(ws + 37748736ULL);           // [36,52MB)  rpe + dcbuf
    bf16*  attnbuf= (bf16*)(ws + 54525952ULL);           // [52,68MB)  [TOK,128]
    bf16*  qkvbuf = (bf16*)(ws + 71303168ULL);           // [68,116MB) [TOK,384]
    bf16*  dwbuf  = qkvbuf;          // last-layer bf16 out (qkvbuf dead by then)
    bf16*  dcbuf  = lnbuf;
    float* rpe    = (float*)lnbuf;   // 1 MB table in lnbuf region

    bf16* wqkv  = wbf;                 // 4 x 384 x 128 (gamma-folded)
    bf16* pproj = wbf + 196608;        // 4 x 16384 packed proj B-frags
    bf16* wpw   = wbf + 786432;        // 256 x 128

    hipLaunchKernelGGL(prep_kernel, dim3(3200), dim3(256), 0, stream,
                       qkv_w, proj_w, fc1_w, fc2_w, pw_w, dw_w, norm1_g,
                       wbf, dwt, stats);
    hipLaunchKernelGGL(foldbias_kernel, dim3(14), dim3(256), 0, stream,
                       qkv_w, qkv_b, norm1_b, fc1_w, fc1_b, norm2_b, fb);
    hipLaunchKernelGGL(pack_kernel, dim3(2048), dim3(256), 0, stream,
                       fc1_w, fc2_w, norm2_g, pw1, pw2);
    hipLaunchKernelGGL(transpose_in_kernel, dim3(1024), dim3(256), 0, stream,
                       x_in, xbuf, tstats);

    const int shifts[4] = {0, 2, 0, 2};
    for (int i = 0; i < 4; ++i) {
        int s = shifts[i];
        // --- attention half: LN (folded) fused into QKV GEMM ---
        hipLaunchKernelGGL(gemm_bf16_kernel, dim3(3, TOK / 128), dim3(256), 0, stream,
                           (const bf16*)nullptr, wqkv + (size_t)i * 49152, fb + i * 384,
                           qkvbuf, xbuf, tstats,
                           (const float*)nullptr, (const float*)nullptr,
                           TOK, 384, 128, 0, s);
        hipLaunchKernelGGL(rpe_expand_kernel, dim3(s ? 1024 : 128), dim3(256), 0, stream,
                           rpb, rpe, i);
        hipLaunchKernelGGL(attn_mfma_kernel, dim3(TOK / 64), dim3(256), 0, stream,
                           qkvbuf, rpe, attnbuf, s);
        // --- fused proj + residual + LN2 + MLP + next-layer LN1 stats ---
        hipLaunchKernelGGL(mlp_kernel, dim3(TOK / 64), dim3(256), 0, stream,
                           xbuf, attnbuf,
                           pproj + (size_t)i * 16384, proj_b + i * 128,
                           pw1 + (size_t)i * 65536, fb + 1536 + i * 512,
                           pw2 + (size_t)i * 65536, fc2_b + i * 128,
                           (i == 3) ? dwbuf : (bf16*)nullptr, tstats, s);
    }

    // connectBlock
    hipLaunchKernelGGL(dwconv_kernel, dim3(1024), dim3(256), 0, stream,
                       dwbuf, dwt, dw_b, dcbuf);
    hipLaunchKernelGGL(gemm_bf16_kernel, dim3(OUTC / 128, TOK / 128), dim3(256), 0, stream,
                       dcbuf, wpw, pw_b,
                       (bf16*)nullptr, (float*)nullptr, stats,
                       (const float*)nullptr, (const float*)nullptr,
                       TOK, OUTC, 128, 4, 0);
    hipLaunchKernelGGL(gemm_bf16_kernel, dim3(OUTC / 128, TOK / 128), dim3(256), 0, stream,
                       dcbuf, wpw, pw_b,
                       (bf16*)nullptr, out, stats,
                       bn_g, bn_b,
                       TOK, OUTC, 128, 5, 0);
}

// Round 12
// 676.949 us; speedup vs baseline: 1.0703x; 1.0013x over previous
//
#include <hip/hip_runtime.h>
#include <hip/hip_bf16.h>
#include <cstddef>
#include <cstdint>

typedef __attribute__((ext_vector_type(8))) short short8;
typedef __attribute__((ext_vector_type(4))) short short4v;
typedef __attribute__((ext_vector_type(4))) float floatx4;
typedef __hip_bfloat16 bf16;

#define HEADS 8
#define TOK   65536
#define OUTC  256

__device__ inline float b2f(short s) {
    union { unsigned u; float f; } x;
    x.u = ((unsigned)(unsigned short)s) << 16;
    return x.f;
}

// 16x16x16 bf16 MFMA. Builtin if present, else raw asm.
__device__ inline floatx4 mfma16(short4v a, short4v b, floatx4 c) {
#if __has_builtin(__builtin_amdgcn_mfma_f32_16x16x16bf16_1k)
    return __builtin_amdgcn_mfma_f32_16x16x16bf16_1k(a, b, c, 0, 0, 0);
#else
    floatx4 d;
    asm volatile("v_mfma_f32_16x16x16_bf16 %0, %1, %2, %3\n\ts_nop 7"
                 : "=v"(d) : "v"(a), "v"(b), "v"(c));
    return d;
#endif
}

// ---------------------------------------------------------------------------
// Transpose input (B,C,32,32,32) -> token-major xbuf[(b*32768+sp)*128 + c]
// + per-token LN stats (mu, rstd) for the layer-0 fused-LN QKV GEMM.
// ---------------------------------------------------------------------------
__global__ __launch_bounds__(256) void transpose_in_kernel(
    const float* __restrict__ x, float* __restrict__ out, float* __restrict__ tstats)
{
    __shared__ float tile[128 * 65];
    int chunk = blockIdx.x;
    int tid = threadIdx.x;
    int b = chunk >> 9;
    int sp0 = (chunk & 511) * 64;
    #pragma unroll
    for (int l = 0; l < 32; ++l) {
        int idx = l * 256 + tid;
        int c = idx >> 6;
        int s = idx & 63;
        tile[c * 65 + s] = x[(((size_t)(b * 128 + c)) << 15) + sp0 + s];
    }
    __syncthreads();
    #pragma unroll
    for (int l = 0; l < 32; ++l) {
        int idx = l * 256 + tid;
        int s = idx >> 7;
        int c = idx & 127;
        out[((size_t)((b << 15) + sp0 + s)) * 128 + c] = tile[c * 65 + s];
    }
    // per-token LN stats: 4 threads per token, 32 channels each
    int s = tid >> 2, q = tid & 3;
    float sm = 0.f, sq = 0.f;
    #pragma unroll
    for (int cc = 0; cc < 32; ++cc) {
        float v = tile[(q * 32 + cc) * 65 + s];
        sm += v; sq += v * v;
    }
    sm += __shfl_xor(sm, 1); sq += __shfl_xor(sq, 1);
    sm += __shfl_xor(sm, 2); sq += __shfl_xor(sq, 2);
    if (q == 0) {
        float mu = sm * (1.0f / 128.0f);
        float var = sq * (1.0f / 128.0f) - mu * mu;
        size_t tok = (size_t)(b << 15) + sp0 + s;
        tstats[tok * 2]     = mu;
        tstats[tok * 2 + 1] = rsqrtf(var + 1e-5f);
    }
}

// ---------------------------------------------------------------------------
// Prep: weight fp32->bf16 conversions + dw-weight transpose + stats zero.
// qkv weights are LN1-gamma-folded. proj weights are packed into MFMA
// B-fragment order for the fused proj+MLP kernel:
//   idx bits wv(2)|ks(2)|nt(1)|lane(6)|j(3) ->
//   proj_w[n = wv*32+nt*16+(lane&15)][k = ks*32+(lane>>4)*8+j]
// ---------------------------------------------------------------------------
__global__ __launch_bounds__(256) void prep_kernel(
    const float* __restrict__ qkv_w, const float* __restrict__ proj_w,
    const float* __restrict__ fc1_w, const float* __restrict__ fc2_w,
    const float* __restrict__ pw_w, const float* __restrict__ dw_w,
    const float* __restrict__ norm1_g,
    bf16* __restrict__ wbf, float* __restrict__ dwt, float* __restrict__ stats)
{
    int i = blockIdx.x * 256 + threadIdx.x;
    float v;
    if (i < 196608) {
        int layer = i / 49152, k = i & 127;
        v = qkv_w[i] * norm1_g[layer * 128 + k];
    }
    else if (i < 262144) {
        int jd = i - 196608;
        int layer = jd >> 14, idx = jd & 16383;
        int j = idx & 7, lane = (idx >> 3) & 63;
        int nt = (idx >> 9) & 1, ks = (idx >> 10) & 3, wvv = (idx >> 12) & 3;
        int row = wvv * 32 + nt * 16 + (lane & 15);
        int col = ks * 32 + (lane >> 4) * 8 + j;
        v = proj_w[layer * 16384 + row * 128 + col];
    }
    else if (i < 524288)  v = fc1_w[i - 262144];
    else if (i < 786432)  v = fc2_w[i - 524288];
    else                  v = pw_w[i - 786432];
    wbf[i] = __float2bfloat16(v);
    if (i < 3456) {
        int c = i / 27, k = i % 27;
        dwt[k * 128 + c] = dw_w[i];
    }
    if (i < 512) stats[i] = 0.f;
}

// ---------------------------------------------------------------------------
// Fold LN betas into biases:
//  fb[0..1536)  : qkvb[l][n]  = qkv_b + sum_k qkv_w[l][n][k]*norm1_b[l][k]
//  fb[1536..3584): b1f[l][n]  = fc1_b + sum_k fc1_w[l][n][k]*norm2_b[l][k]
// ---------------------------------------------------------------------------
__global__ __launch_bounds__(256) void foldbias_kernel(
    const float* __restrict__ qkv_w, const float* __restrict__ qkv_b,
    const float* __restrict__ norm1_b,
    const float* __restrict__ fc1_w, const float* __restrict__ fc1_b,
    const float* __restrict__ norm2_b, float* __restrict__ fb)
{
    int t = blockIdx.x * 256 + threadIdx.x;
    if (t < 1536) {
        int l = t / 384, n = t % 384;
        const float* wr = qkv_w + (size_t)l * 49152 + n * 128;
        const float* br = norm1_b + l * 128;
        float s = qkv_b[t];
        #pragma unroll 4
        for (int k = 0; k < 128; ++k) s += wr[k] * br[k];
        fb[t] = s;
    } else if (t < 3584) {
        int u = t - 1536;
        int l = u >> 9, n = u & 511;
        const float* wr = fc1_w + (size_t)l * 65536 + n * 128;
        const float* br = norm2_b + l * 128;
        float s = fc1_b[l * 512 + n];
        #pragma unroll 4
        for (int k = 0; k < 128; ++k) s += wr[k] * br[k];
        fb[t] = s;
    }
}

// ---------------------------------------------------------------------------
// Pack fc1/fc2 weights into MFMA-fragment order for the 4-chunk MLP.
// pw1 is LN2-gamma-folded (gamma indexes the k dimension = col).
// pw1 flat idx bits: cc(2)|wv(2)|kk(2)|nt(1)|lane(6)|j(3) ->
//   fc1_w[row = cc*128 + wv*32 + nt*16 + (lane&15)][col = kk*32 + (lane>>4)*8 + j]
// pw2 flat idx bits: wv(2)|cc(2)|ks(2)|nt(1)|lane(6)|j(3) ->
//   fc2_w[row = wv*32 + nt*16 + (lane&15)][col = cc*128 + ks*32 + (lane>>4)*8 + j]
// ---------------------------------------------------------------------------
__global__ __launch_bounds__(256) void pack_kernel(
    const float* __restrict__ fc1_w, const float* __restrict__ fc2_w,
    const float* __restrict__ norm2_g,
    bf16* __restrict__ pw1, bf16* __restrict__ pw2)
{
    int t = blockIdx.x * 256 + threadIdx.x;
    int i = t >> 17;
    int rem = t & 131071;
    int type = rem >> 16;
    int idx = rem & 65535;
    int j = idx & 7, lane = (idx >> 3) & 63;
    int ln15 = lane & 15, quad = lane >> 4;
    if (type == 0) {
        int nt = (idx >> 9) & 1, kk = (idx >> 10) & 3, wv = (idx >> 12) & 3, cc = (idx >> 14) & 3;
        int row = cc * 128 + wv * 32 + nt * 16 + ln15;
        int col = kk * 32 + quad * 8 + j;
        pw1[i * 65536 + idx] = __float2bfloat16(
            fc1_w[(size_t)i * 65536 + row * 128 + col] * norm2_g[i * 128 + col]);
    } else {
        int nt = (idx >> 9) & 1, ks = (idx >> 10) & 3, cc = (idx >> 12) & 3, wv = (idx >> 14) & 3;
        int row = wv * 32 + nt * 16 + ln15;
        int col = cc * 128 + ks * 32 + quad * 8 + j;
        pw2[i * 65536 + idx] = __float2bfloat16(fc2_w[(size_t)i * 65536 + row * 512 + col]);
    }
}

// ---------------------------------------------------------------------------
// Expand relative-position bias + shift mask into rpe[wtype][head][64][64] f32.
// ---------------------------------------------------------------------------
__global__ __launch_bounds__(256) void rpe_expand_kernel(
    const float* __restrict__ rpb, float* __restrict__ rpe, int layer)
{
    int t = blockIdx.x * 256 + threadIdx.x;
    int j = t & 63, i = (t >> 6) & 63, head = (t >> 12) & 7, wt = t >> 15;
    int ih = i >> 4, iw = (i >> 2) & 3, it = i & 3;
    int jh = j >> 4, jw = (j >> 2) & 3, jt = j & 3;
    int ridx = ((ih - jh + 3) * 7 + (iw - jw + 3)) * 7 + (it - jt + 3);
    float v = rpb[layer * 2744 + ridx * 8 + head];
    if (wt) {
        bool ok = true;
        if (wt & 4) ok = ok && ((ih >= 2) == (jh >= 2));
        if (wt & 2) ok = ok && ((iw >= 2) == (jw >= 2));
        if (wt & 1) ok = ok && ((it >= 2) == (jt >= 2));
        if (!ok) v -= 100.f;
    }
    rpe[t] = v;
}

// ---------------------------------------------------------------------------
// bf16 MFMA GEMM with coalesced LDS-staged epilogues.
// mode 0 (QKV): A-staging gathers fp32 rows from xbuf (Cf) with the shift-
// window token map and applies bf16((x-mu)*rstd) — gamma/beta folded into
// weights/bias. q columns (nBase==0) pre-scaled 0.25 in epilogue.
// mode 4/5: pointwise-conv stats / BN+ReLU epilogues (connectBlock).
// ---------------------------------------------------------------------------
__global__ __launch_bounds__(256) void gemm_bf16_kernel(
    const bf16* __restrict__ A, const bf16* __restrict__ Bw,
    const float* __restrict__ bias, bf16* __restrict__ Cb, float* __restrict__ Cf,
    float* __restrict__ aux, const float* __restrict__ p1, const float* __restrict__ p2,
    int M, int N, int K, int mode, int shift)
{
    __shared__ __align__(16) char smem[34816];
    __shared__ float cs[128];
    __shared__ float cq[128];
    short* As = (short*)smem;
    short* Bs = (short*)(smem + 8192);
    int tid = threadIdx.x;
    int lane = tid & 63, wv = tid >> 6;
    int wm = wv >> 1, wn = wv & 1;
    int ln15 = lane & 15, quad = lane >> 4;
    int q8 = quad * 8;
    int nBase = blockIdx.x * 128;
    int mBase = blockIdx.y * 128;
    floatx4 acc[4][4] = {};

    if (mode == 4 && tid < 128) { cs[tid] = 0.f; cq[tid] = 0.f; }

    int srow = tid >> 2, scb = tid & 3;

    int toks[2]; float tmu[2], trs[2];
    if (mode == 0) {
        #pragma unroll
        for (int i = 0; i < 2; ++i) {
            int m = mBase + srow + i * 64;
            int n = m & 63, w = (m >> 6) & 511, b = m >> 15;
            int ih = n >> 4, iw = (n >> 2) & 3, it = n & 3;
            int wh = w >> 6, ww = (w >> 3) & 7, wt = w & 7;
            int h  = (wh * 4 + ih + shift) & 31;
            int w2 = (ww * 4 + iw + shift) & 31;
            int t  = (wt * 4 + it + shift) & 31;
            toks[i] = (b << 15) + ((h * 32 + w2) * 32 + t);
            tmu[i] = aux[(size_t)toks[i] * 2];
            trs[i] = aux[(size_t)toks[i] * 2 + 1];
        }
    }

    for (int k0 = 0; k0 < K; k0 += 32) {
        if (mode == 0) {
            int cb = k0 + scb * 8;
            #pragma unroll
            for (int i = 0; i < 2; ++i) {
                const float* xr = Cf + (size_t)toks[i] * 128 + cb;
                float4 a0 = *(const float4*)xr;
                float4 a1 = *(const float4*)(xr + 4);
                float mu = tmu[i], rs = trs[i];
                __align__(16) bf16 pk[8];
                pk[0] = __float2bfloat16((a0.x - mu) * rs);
                pk[1] = __float2bfloat16((a0.y - mu) * rs);
                pk[2] = __float2bfloat16((a0.z - mu) * rs);
                pk[3] = __float2bfloat16((a0.w - mu) * rs);
                pk[4] = __float2bfloat16((a1.x - mu) * rs);
                pk[5] = __float2bfloat16((a1.y - mu) * rs);
                pk[6] = __float2bfloat16((a1.z - mu) * rs);
                pk[7] = __float2bfloat16((a1.w - mu) * rs);
                ((uint4*)As)[i * 256 + tid] = *(const uint4*)pk;
                ((uint4*)Bs)[i * 256 + tid] =
                    *(const uint4*)(Bw + (size_t)(nBase + srow + i * 64) * K + cb);
            }
        } else {
            #pragma unroll
            for (int i = 0; i < 2; ++i) {
                int row = srow + i * 64;
                ((uint4*)As)[i * 256 + tid] =
                    *(const uint4*)(A + (size_t)(mBase + row) * K + k0 + scb * 8);
                ((uint4*)Bs)[i * 256 + tid] =
                    *(const uint4*)(Bw + (size_t)(nBase + row) * K + k0 + scb * 8);
            }
        }
        __syncthreads();
        short8 af[4], bfr[4];
        #pragma unroll
        for (int mt = 0; mt < 4; ++mt)
            af[mt] = *(const short8*)&As[(wm * 64 + mt * 16 + ln15) * 32 + q8];
        #pragma unroll
        for (int nt = 0; nt < 4; ++nt)
            bfr[nt] = *(const short8*)&Bs[(wn * 64 + nt * 16 + ln15) * 32 + q8];
        #pragma unroll
        for (int mt = 0; mt < 4; ++mt)
            #pragma unroll
            for (int nt = 0; nt < 4; ++nt)
                acc[mt][nt] = __builtin_amdgcn_mfma_f32_16x16x32_bf16(
                    af[mt], bfr[nt], acc[mt][nt], 0, 0, 0);
        __syncthreads();
    }

    if (mode == 4) {
        #pragma unroll
        for (int nt = 0; nt < 4; ++nt) {
            int nl = wn * 64 + nt * 16 + ln15;
            float bs = bias[nBase + nl];
            float s = 0.f, sq = 0.f;
            #pragma unroll
            for (int mt = 0; mt < 4; ++mt)
                #pragma unroll
                for (int r = 0; r < 4; ++r) {
                    float v = acc[mt][nt][r] + bs;
                    s += v; sq += v * v;
                }
            atomicAdd(&cs[nl], s);
            atomicAdd(&cq[nl], sq);
        }
        __syncthreads();
        if (tid < 128) {
            atomicAdd(&aux[nBase + tid], cs[tid]);
            atomicAdd(&aux[256 + nBase + tid], cq[tid]);
        }
        return;
    }

    if (mode == 0) {
        bf16* estage = (bf16*)smem;          // [128][136]
        float qsc = (nBase == 0) ? 0.25f : 1.0f;
        #pragma unroll
        for (int mt = 0; mt < 4; ++mt)
            #pragma unroll
            for (int nt = 0; nt < 4; ++nt)
                #pragma unroll
                for (int r = 0; r < 4; ++r) {
                    int row = wm * 64 + mt * 16 + quad * 4 + r;
                    int col = wn * 64 + nt * 16 + ln15;
                    estage[row * 136 + col] =
                        __float2bfloat16((acc[mt][nt][r] + bias[nBase + col]) * qsc);
                }
        __syncthreads();
        int row = tid >> 1, hf = tid & 1;
        #pragma unroll
        for (int j = 0; j < 4; ++j) {
            int col = hf * 64 + j * 16;
            *(uint4*)(Cb + (size_t)(mBase + row) * N + nBase + col) =
                *(const uint4*)&estage[row * 136 + col];
            *(uint4*)(Cb + (size_t)(mBase + row) * N + nBase + col + 8) =
                *(const uint4*)&estage[row * 136 + col + 8];
        }
        return;
    }

    // mode 5: BN + ReLU + transposed store
    {
        float* fstage = (float*)smem;        // [64 nn][132 sp]
        int b = mBase >> 15, sp0 = mBase & 32767;
        #pragma unroll
        for (int hf = 0; hf < 2; ++hf) {
            if (wn == hf) {
                #pragma unroll
                for (int nt = 0; nt < 4; ++nt) {
                    int ncol = nt * 16 + ln15;
                    int nn = nBase + hf * 64 + ncol;
                    float mean = aux[nn] * (1.0f / 65536.0f);
                    float var  = aux[256 + nn] * (1.0f / 65536.0f) - mean * mean;
                    float sc = rsqrtf(var + 1e-5f) * p1[nn];
                    float off = p2[nn] + bias[nn] * sc - mean * sc;
                    #pragma unroll
                    for (int mt = 0; mt < 4; ++mt)
                        #pragma unroll
                        for (int r = 0; r < 4; ++r) {
                            int ml = wm * 64 + mt * 16 + quad * 4 + r;
                            float y = acc[mt][nt][r] * sc + off;
                            fstage[ncol * 132 + ml] = fmaxf(y, 0.f);
                        }
                }
            }
            __syncthreads();
            int nl = tid >> 2, part = tid & 3;
            int nn = nBase + hf * 64 + nl;
            float* dst = Cf + (((size_t)(b * 256 + nn)) << 15) + sp0 + part * 32;
            #pragma unroll
            for (int j = 0; j < 8; ++j)
                *(float4*)(dst + j * 4) = *(const float4*)&fstage[nl * 132 + part * 32 + j * 4];
            __syncthreads();
        }
    }
}

// ---------------------------------------------------------------------------
// Fused proj + residual + LN2 + MLP (v7.4). Each block = 64 natural-order
// tokens; x_mid round-tripped through xbuf. Occupancy is pinned via the
// NATIVE attribute list (no __launch_bounds__ macro): clang's launch_bounds
// lowering overrode amdgpu_waves_per_eu in R11 (VGPR stayed 64, ~23 MB
// scratch/dispatch). amdgpu_flat_work_group_size(256,256) +
// amdgpu_waves_per_eu(4,4) pins 4 waves/EU -> 128-VGPR budget, spill-free
// for the ~108-reg live set. 4 blocks/CU, LDS 4x34 KB = 136 KB.
// ---------------------------------------------------------------------------
__global__
__attribute__((amdgpu_flat_work_group_size(256, 256), amdgpu_waves_per_eu(4, 4)))
void mlp_kernel(
    float* __restrict__ xbuf, const bf16* __restrict__ attnbuf,
    const bf16* __restrict__ ppw, const float* __restrict__ pb,
    const bf16* __restrict__ pw1, const float* __restrict__ b1,
    const bf16* __restrict__ pw2, const float* __restrict__ b2,
    bf16* __restrict__ xout16, float* __restrict__ tstats, int shift)
{
    __shared__ __align__(16) bf16 smem[64 * 136 * 2];   // 34 KB
    bf16* aln  = smem;              // [64][136] atile / LN2'd x_mid
    bf16* hidc = smem + 64 * 136;   // [64][136] per-chunk hidden
    float* ostage = (float*)smem;   // [64][132] f32, full-smem alias
    int tid = threadIdx.x;
    int lane = tid & 63, wv = tid >> 6;
    int ln15 = lane & 15, quad = lane >> 4;
    int q8 = quad * 8;
    int blk = blockIdx.x;
    size_t tok0 = (size_t)blk * 64;
    int b = blk >> 9, h = (blk >> 4) & 31, wpair = blk & 15;

    // 1. gather attnbuf (window order) -> atile rows in natural-local order
    #pragma unroll
    for (int l = 0; l < 4; ++l) {
        int q = l * 256 + tid;
        int row = q >> 4, c16 = q & 15;
        int w2 = wpair * 2 + (row >> 5), t = row & 31;
        int hs = (h - shift) & 31, ws = (w2 - shift) & 31, ts = (t - shift) & 31;
        int wr = (b << 15) + (((hs >> 2) * 64 + ((ws >> 2) << 3) + (ts >> 2)) << 6)
               + ((hs & 3) * 16 + ((ws & 3) << 2) + (ts & 3));
        *(uint4*)&aln[row * 136 + c16 * 8] =
            *(const uint4*)((const short*)attnbuf + (size_t)wr * 128 + c16 * 8);
    }
    __syncthreads();

    // 2. proj: out[64][128]; wave wv -> cols wv*32..+31, K=128
    floatx4 accp[4][2] = {};
    #pragma unroll
    for (int ks = 0; ks < 4; ++ks) {
        short8 af[4], bfr[2];
        #pragma unroll
        for (int mt = 0; mt < 4; ++mt)
            af[mt] = *(const short8*)&aln[(mt * 16 + ln15) * 136 + ks * 32 + q8];
        #pragma unroll
        for (int nt = 0; nt < 2; ++nt)
            bfr[nt] = *(const short8*)(ppw + wv * 4096 + ks * 1024 + nt * 512 + lane * 8);
        #pragma unroll
        for (int mt = 0; mt < 4; ++mt)
            #pragma unroll
            for (int nt = 0; nt < 2; ++nt)
                accp[mt][nt] = __builtin_amdgcn_mfma_f32_16x16x32_bf16(
                    af[mt], bfr[nt], accp[mt][nt], 0, 0, 0);
    }
    __syncthreads();   // atile dead -> ostage (full smem)

    #pragma unroll
    for (int mt = 0; mt < 4; ++mt)
        #pragma unroll
        for (int nt = 0; nt < 2; ++nt)
            #pragma unroll
            for (int r = 0; r < 4; ++r) {
                int m = mt * 16 + quad * 4 + r;
                int n = wv * 32 + nt * 16 + ln15;
                ostage[m * 132 + n] = accp[mt][nt][r] + pb[n];
            }
    __syncthreads();

    // 3+4. x_mid = xbuf + proj -> xbuf; LN2 (folded) -> aln bf16.
    // Buffer v/mu/rs in regs across one barrier (ostage/aln alias), then
    // write aln after the barrier.
    float4 vsave[8];
    float musave[8], rssave[8];
    #pragma unroll
    for (int jj = 0; jj < 8; ++jj) {
        int idx = (jj * 256 + tid) * 4;
        int t = idx >> 7, c = idx & 127;
        float4 v = *(const float4*)(xbuf + tok0 * 128 + idx);
        float4 o = *(const float4*)&ostage[t * 132 + c];
        v.x += o.x; v.y += o.y; v.z += o.z; v.w += o.w;
        *(float4*)(xbuf + tok0 * 128 + idx) = v;
        float ps = v.x + v.y + v.z + v.w;
        float pq = v.x * v.x + v.y * v.y + v.z * v.z + v.w * v.w;
        #pragma unroll
        for (int o2 = 16; o2 > 0; o2 >>= 1) {
            ps += __shfl_xor(ps, o2); pq += __shfl_xor(pq, o2);
        }
        float mu = ps * (1.0f / 128.0f);
        float var = pq * (1.0f / 128.0f) - mu * mu;
        vsave[jj] = v;
        musave[jj] = mu;
        rssave[jj] = rsqrtf(var + 1e-5f);
    }
    __syncthreads();   // all ostage reads done -> aln region reusable
    #pragma unroll
    for (int jj = 0; jj < 8; ++jj) {
        int idx = (jj * 256 + tid) * 4;
        int t = idx >> 7, c = idx & 127;
        float4 v = vsave[jj];
        float mu = musave[jj], rs = rssave[jj];
        __align__(8) bf16 hh[4];
        hh[0] = __float2bfloat16((v.x - mu) * rs);
        hh[1] = __float2bfloat16((v.y - mu) * rs);
        hh[2] = __float2bfloat16((v.z - mu) * rs);
        hh[3] = __float2bfloat16((v.w - mu) * rs);
        *(uint2*)&aln[t * 136 + c] = *(const uint2*)hh;
    }
    __syncthreads();

    // 5. 4-chunk MLP (R5-proven)
    floatx4 acc2[4][2] = {};
    #pragma unroll
    for (int cc = 0; cc < 4; ++cc) {
        floatx4 acc[4][2] = {};
        const bf16* p1w = pw1 + (size_t)(cc * 4 + wv) * 4096;
        #pragma unroll
        for (int kk = 0; kk < 4; ++kk) {
            short8 af[4], bfr[2];
            #pragma unroll
            for (int mt = 0; mt < 4; ++mt)
                af[mt] = *(const short8*)&aln[(mt * 16 + ln15) * 136 + kk * 32 + q8];
            #pragma unroll
            for (int nt = 0; nt < 2; ++nt)
                bfr[nt] = *(const short8*)(p1w + kk * 1024 + nt * 512 + lane * 8);
            #pragma unroll
            for (int mt = 0; mt < 4; ++mt)
                #pragma unroll
                for (int nt = 0; nt < 2; ++nt)
                    acc[mt][nt] = __builtin_amdgcn_mfma_f32_16x16x32_bf16(
                        af[mt], bfr[nt], acc[mt][nt], 0, 0, 0);
        }
        if (cc) __syncthreads();
        #pragma unroll
        for (int mt = 0; mt < 4; ++mt)
            #pragma unroll
            for (int nt = 0; nt < 2; ++nt)
                #pragma unroll
                for (int r = 0; r < 4; ++r) {
                    int m = mt * 16 + quad * 4 + r;
                    int ncl = wv * 32 + nt * 16 + ln15;
                    float v = acc[mt][nt][r] + b1[cc * 128 + ncl];
                    float u = v * (0.7978845608f + 0.0356774081f * v * v);
                    v = v * __builtin_amdgcn_rcpf(1.f + __expf(-2.f * u));
                    hidc[m * 136 + ncl] = __float2bfloat16(v);
                }
        __syncthreads();
        const bf16* p2w = pw2 + (size_t)(wv * 4 + cc) * 4096;
        #pragma unroll
        for (int ks = 0; ks < 4; ++ks) {
            short8 af[4], bfr[2];
            #pragma unroll
            for (int mt = 0; mt < 4; ++mt)
                af[mt] = *(const short8*)&hidc[(mt * 16 + ln15) * 136 + ks * 32 + q8];
            #pragma unroll
            for (int nt = 0; nt < 2; ++nt)
                bfr[nt] = *(const short8*)(p2w + ks * 1024 + nt * 512 + lane * 8);
            #pragma unroll
            for (int mt = 0; mt < 4; ++mt)
                #pragma unroll
                for (int nt = 0; nt < 2; ++nt)
                    acc2[mt][nt] = __builtin_amdgcn_mfma_f32_16x16x32_bf16(
                        af[mt], bfr[nt], acc2[mt][nt], 0, 0, 0);
        }
    }
    __syncthreads();   // aln/hidc dead -> ostage2 (full smem)

    #pragma unroll
    for (int mt = 0; mt < 4; ++mt)
        #pragma unroll
        for (int nt = 0; nt < 2; ++nt)
            #pragma unroll
            for (int r = 0; r < 4; ++r) {
                int m = mt * 16 + quad * 4 + r;
                int n = wv * 32 + nt * 16 + ln15;
                ostage[m * 132 + n] = acc2[mt][nt][r] + b2[n];
            }
    __syncthreads();

    // 6. final residual: re-read own x_mid lines + MLP out; next-layer stats
    #pragma unroll
    for (int jj = 0; jj < 8; ++jj) {
        int idx = (jj * 256 + tid) * 4;
        int t = idx >> 7, c = idx & 127;
        float4 v = *(const float4*)(xbuf + tok0 * 128 + idx);
        float4 o = *(const float4*)&ostage[t * 132 + c];
        v.x += o.x; v.y += o.y; v.z += o.z; v.w += o.w;
        *(float4*)(xbuf + tok0 * 128 + idx) = v;
        if (xout16) {
            __align__(8) bf16 hh[4];
            hh[0] = __float2bfloat16(v.x); hh[1] = __float2bfloat16(v.y);
            hh[2] = __float2bfloat16(v.z); hh[3] = __float2bfloat16(v.w);
            *(uint2*)(xout16 + tok0 * 128 + idx) = *(const uint2*)hh;
        }
        float ps = v.x + v.y + v.z + v.w;
        float pq = v.x * v.x + v.y * v.y + v.z * v.z + v.w * v.w;
        #pragma unroll
        for (int o2 = 16; o2 > 0; o2 >>= 1) {
            ps += __shfl_xor(ps, o2); pq += __shfl_xor(pq, o2);
        }
        if ((tid & 31) == 0) {
            float mu = ps * (1.0f / 128.0f);
            float var = pq * (1.0f / 128.0f) - mu * mu;
            size_t tok = tok0 + t;
            tstats[tok * 2]     = mu;
            tstats[tok * 2 + 1] = rsqrtf(var + 1e-5f);
        }
    }
}

// ---------------------------------------------------------------------------
// MFMA windowed attention (unchanged).
// ---------------------------------------------------------------------------
__global__ __launch_bounds__(256, 3) void attn_mfma_kernel(
    const bf16* __restrict__ qkv, const float* __restrict__ rpe,
    bf16* __restrict__ outp, int shift)
{
    __shared__ __align__(16) short qs[64 * 392];   // 49 KB; reused as O stage
    int tid = threadIdx.x;
    int lane = tid & 63, wv = tid >> 6;
    int ln15 = lane & 15, quad = lane >> 4;
    int win = blockIdx.x;
    size_t tok0 = (size_t)win * 64;

    const short* gq = (const short*)qkv + tok0 * 384;
    #pragma unroll
    for (int l = 0; l < 12; ++l) {
        int idx = l * 256 + tid;
        int r = idx / 48, c = idx - r * 48;
        *(uint4*)&qs[r * 392 + c * 8] = *(const uint4*)&gq[r * 384 + c * 8];
    }
    int w = win & 511;
    int wtype = 0;
    if (shift)
        wtype = (((w >> 6) == 7) << 2) | ((((w >> 3) & 7) == 7) << 1) | (int)((w & 7) == 7);
    const float* rpw = rpe + ((size_t)(wtype * 8) << 12);
    __syncthreads();

    floatx4 oacc[2][4];
    #pragma unroll
    for (int hh = 0; hh < 2; ++hh) {
        int head = wv * 2 + hh;
        const float* rph = rpw + ((size_t)head << 12);

        floatx4 acc[4][4];
        #pragma unroll
        for (int jt = 0; jt < 4; ++jt)
            #pragma unroll
            for (int it = 0; it < 4; ++it)
                acc[jt][it] = *(const floatx4*)&rph[(it * 16 + ln15) * 64 + jt * 16 + quad * 4];

        short4v qf[4], kf[4];
        #pragma unroll
        for (int it = 0; it < 4; ++it)
            qf[it] = *(const short4v*)&qs[(it * 16 + ln15) * 392 + head * 16 + quad * 4];
        #pragma unroll
        for (int jt = 0; jt < 4; ++jt)
            kf[jt] = *(const short4v*)&qs[(jt * 16 + ln15) * 392 + 128 + head * 16 + quad * 4];

        #pragma unroll
        for (int jt = 0; jt < 4; ++jt)
            #pragma unroll
            for (int it = 0; it < 4; ++it)
                acc[jt][it] = mfma16(kf[jt], qf[it], acc[jt][it]);

        short4v pf[4][4];
        #pragma unroll
        for (int it = 0; it < 4; ++it) {
            float m = -1e30f;
            #pragma unroll
            for (int jt = 0; jt < 4; ++jt)
                #pragma unroll
                for (int r = 0; r < 4; ++r) m = fmaxf(m, acc[jt][it][r]);
            m = fmaxf(m, __shfl_xor(m, 16));
            m = fmaxf(m, __shfl_xor(m, 32));
            float s = 0.f;
            #pragma unroll
            for (int jt = 0; jt < 4; ++jt)
                #pragma unroll
                for (int r = 0; r < 4; ++r) {
                    float e = __expf(acc[jt][it][r] - m);
                    acc[jt][it][r] = e; s += e;
                }
            s += __shfl_xor(s, 16);
            s += __shfl_xor(s, 32);
            float inv = 1.0f / s;
            #pragma unroll
            for (int jt = 0; jt < 4; ++jt) {
                __align__(8) bf16 pb[4];
                #pragma unroll
                for (int r = 0; r < 4; ++r)
                    pb[r] = __float2bfloat16(acc[jt][it][r] * inv);
                pf[jt][it] = *(const short4v*)pb;
            }
        }

        short4v vf[4];
        #pragma unroll
        for (int jt = 0; jt < 4; ++jt)
            #pragma unroll
            for (int jj = 0; jj < 4; ++jj)
                vf[jt][jj] = qs[(jt * 16 + quad * 4 + jj) * 392 + 256 + head * 16 + ln15];

        #pragma unroll
        for (int it = 0; it < 4; ++it) {
            floatx4 o = {0.f, 0.f, 0.f, 0.f};
            #pragma unroll
            for (int jt = 0; jt < 4; ++jt)
                o = mfma16(vf[jt], pf[jt][it], o);
            oacc[hh][it] = o;
        }
    }
    __syncthreads();   // all qs reads done -> reuse as O stage [64][136]

    short* ob = qs;
    #pragma unroll
    for (int hh = 0; hh < 2; ++hh)
        #pragma unroll
        for (int it = 0; it < 4; ++it) {
            __align__(8) bf16 t4[4];
            #pragma unroll
            for (int r = 0; r < 4; ++r) t4[r] = __float2bfloat16(oacc[hh][it][r]);
            *(short4v*)&ob[(it * 16 + ln15) * 136 + (wv * 2 + hh) * 16 + quad * 4] =
                *(const short4v*)t4;
        }
    __syncthreads();

    short* po = (short*)outp + tok0 * 128;
    #pragma unroll
    for (int l = 0; l < 4; ++l) {
        int idx = l * 256 + tid;
        int r = idx >> 4, c = idx & 15;
        *(uint4*)&po[r * 128 + c * 8] = *(const uint4*)&ob[r * 136 + c * 8];
    }
}

// ---------------------------------------------------------------------------
// Depthwise 3x3x3 conv v2 (unchanged).
// ---------------------------------------------------------------------------
__global__ __launch_bounds__(256) void dwconv_kernel(
    const bf16* __restrict__ x, const float* __restrict__ dwt,
    const float* __restrict__ bias, bf16* __restrict__ out)
{
    int blk = blockIdx.x;                  // b(1) | h(5) | wpair(4)
    int b = blk >> 9;
    int h = (blk >> 4) & 31;
    int w = ((blk & 15) << 1) | (threadIdx.x >> 7);
    int tid = threadIdx.x & 127;
    int c0 = (tid & 31) * 4;
    int t0 = (tid >> 5) * 8;

    float4 acc[8];
    float4 bs = *(const float4*)&bias[c0];
    #pragma unroll
    for (int o = 0; o < 8; ++o) acc[o] = bs;

    #pragma unroll
    for (int kh = 0; kh < 3; ++kh) {
        int hh = h + kh - 1;
        if (hh < 0 || hh > 31) continue;
        #pragma unroll
        for (int kw = 0; kw < 3; ++kw) {
            int ww = w + kw - 1;
            if (ww < 0 || ww > 31) continue;
            const short* px = (const short*)x +
                ((size_t)(b << 15) + (hh * 32 + ww) * 32) * 128 + c0;
            float4 v[10];
            #pragma unroll
            for (int u = 0; u < 10; ++u) {
                int tt = t0 - 1 + u;
                if (tt >= 0 && tt < 32) {
                    short4v s4 = *(const short4v*)(px + (size_t)tt * 128);
                    v[u].x = b2f(s4[0]); v[u].y = b2f(s4[1]);
                    v[u].z = b2f(s4[2]); v[u].w = b2f(s4[3]);
                } else {
                    v[u].x = v[u].y = v[u].z = v[u].w = 0.f;
                }
            }
            int kb = kh * 9 + kw * 3;
            float4 w0 = *(const float4*)&dwt[(kb + 0) * 128 + c0];
            float4 w1 = *(const float4*)&dwt[(kb + 1) * 128 + c0];
            float4 w2 = *(const float4*)&dwt[(kb + 2) * 128 + c0];
            #pragma unroll
            for (int o = 0; o < 8; ++o) {
                acc[o].x += v[o].x * w0.x + v[o + 1].x * w1.x + v[o + 2].x * w2.x;
                acc[o].y += v[o].y * w0.y + v[o + 1].y * w1.y + v[o + 2].y * w2.y;
                acc[o].z += v[o].z * w0.z + v[o + 1].z * w1.z + v[o + 2].z * w2.z;
                acc[o].w += v[o].w * w0.w + v[o + 1].w * w1.w + v[o + 2].w * w2.w;
            }
        }
    }
    short* po = (short*)out + ((size_t)(b << 15) + (h * 32 + w) * 32 + t0) * 128 + c0;
    #pragma unroll
    for (int o = 0; o < 8; ++o) {
        __align__(8) bf16 h4[4];
        h4[0] = __float2bfloat16(acc[o].x);
        h4[1] = __float2bfloat16(acc[o].y);
        h4[2] = __float2bfloat16(acc[o].z);
        h4[3] = __float2bfloat16(acc[o].w);
        *(uint2*)(po + (size_t)o * 128) = *(const uint2*)h4;
    }
}

// ---------------------------------------------------------------------------
extern "C" void kernel_launch(void* const* d_in, const int* in_sizes, int n_in,
                              void* d_out, int out_size, void* d_ws, size_t ws_size,
                              hipStream_t stream)
{
    const float* x_in    = (const float*)d_in[0];
    const float* norm1_g = (const float*)d_in[1];
    const float* norm1_b = (const float*)d_in[2];
    const float* qkv_w   = (const float*)d_in[3];
    const float* qkv_b   = (const float*)d_in[4];
    const float* proj_w  = (const float*)d_in[5];
    const float* proj_b  = (const float*)d_in[6];
    const float* rpb     = (const float*)d_in[7];
    const float* norm2_g = (const float*)d_in[8];
    const float* norm2_b = (const float*)d_in[9];
    const float* fc1_w   = (const float*)d_in[10];
    const float* fc1_b   = (const float*)d_in[11];
    const float* fc2_w   = (const float*)d_in[12];
    const float* fc2_b   = (const float*)d_in[13];
    const float* dw_w    = (const float*)d_in[14];
    const float* dw_b    = (const float*)d_in[15];
    const float* pw_w    = (const float*)d_in[16];
    const float* pw_b    = (const float*)d_in[17];
    const float* bn_g    = (const float*)d_in[18];
    const float* bn_b    = (const float*)d_in[19];
    float* out = (float*)d_out;

    char* ws = (char*)d_ws;
    float* xbuf   = (float*)ws;                          // [0,32MB)   fp32 [TOK,128]
    bf16*  wbf    = (bf16*)(ws + 33554432ULL);           // [32,34MB)  bf16 weights
    float* dwt    = (float*)(ws + 35651584ULL);          // 27x128 fp32
    float* stats  = (float*)(ws + 35717120ULL);          // 2 KB
    float* fb     = (float*)(ws + 35719168ULL);          // 14 KB folded biases
    bf16*  pw1    = (bf16*)(ws + 35782656ULL);           // 512 KB packed fc1
    bf16*  pw2    = (bf16*)(ws + 36306944ULL);           // 512 KB packed fc2
    float* tstats = (float*)(ws + 36831232ULL);          // 512 KB per-token LN stats
    bf16*  lnbuf  = (bf16*)(ws + 37748736ULL);           // [36,52MB)  rpe + dcbuf
    bf16*  attnbuf= (bf16*)(ws + 54525952ULL);           // [52,68MB)  [TOK,128]
    bf16*  qkvbuf = (bf16*)(ws + 71303168ULL);           // [68,116MB) [TOK,384]
    bf16*  dwbuf  = qkvbuf;          // last-layer bf16 out (qkvbuf dead by then)
    bf16*  dcbuf  = lnbuf;
    float* rpe    = (float*)lnbuf;   // 1 MB table in lnbuf region

    bf16* wqkv  = wbf;                 // 4 x 384 x 128 (gamma-folded)
    bf16* pproj = wbf + 196608;        // 4 x 16384 packed proj B-frags
    bf16* wpw   = wbf + 786432;        // 256 x 128

    hipLaunchKernelGGL(prep_kernel, dim3(3200), dim3(256), 0, stream,
                       qkv_w, proj_w, fc1_w, fc2_w, pw_w, dw_w, norm1_g,
                       wbf, dwt, stats);
    hipLaunchKernelGGL(foldbias_kernel, dim3(14), dim3(256), 0, stream,
                       qkv_w, qkv_b, norm1_b, fc1_w, fc1_b, norm2_b, fb);
    hipLaunchKernelGGL(pack_kernel, dim3(2048), dim3(256), 0, stream,
                       fc1_w, fc2_w, norm2_g, pw1, pw2);
    hipLaunchKernelGGL(transpose_in_kernel, dim3(1024), dim3(256), 0, stream,
                       x_in, xbuf, tstats);

    const int shifts[4] = {0, 2, 0, 2};
    for (int i = 0; i < 4; ++i) {
        int s = shifts[i];
        // --- attention half: LN (folded) fused into QKV GEMM ---
        hipLaunchKernelGGL(gemm_bf16_kernel, dim3(3, TOK / 128), dim3(256), 0, stream,
                           (const bf16*)nullptr, wqkv + (size_t)i * 49152, fb + i * 384,
                           qkvbuf, xbuf, tstats,
                           (const float*)nullptr, (const float*)nullptr,
                           TOK, 384, 128, 0, s);
        hipLaunchKernelGGL(rpe_expand_kernel, dim3(s ? 1024 : 128), dim3(256), 0, stream,
                           rpb, rpe, i);
        hipLaunchKernelGGL(attn_mfma_kernel, dim3(TOK / 64), dim3(256), 0, stream,
                           qkvbuf, rpe, attnbuf, s);
        // --- fused proj + residual + LN2 + MLP + next-layer LN1 stats ---
        hipLaunchKernelGGL(mlp_kernel, dim3(TOK / 64), dim3(256), 0, stream,
                           xbuf, attnbuf,
                           pproj + (size_t)i * 16384, proj_b + i * 128,
                           pw1 + (size_t)i * 65536, fb + 1536 + i * 512,
                           pw2 + (size_t)i * 65536, fc2_b + i * 128,
                           (i == 3) ? dwbuf : (bf16*)nullptr, tstats, s);
    }

    // connectBlock
    hipLaunchKernelGGL(dwconv_kernel, dim3(1024), dim3(256), 0, stream,
                       dwbuf, dwt, dw_b, dcbuf);
    hipLaunchKernelGGL(gemm_bf16_kernel, dim3(OUTC / 128, TOK / 128), dim3(256), 0, stream,
                       dcbuf, wpw, pw_b,
                       (bf16*)nullptr, (float*)nullptr, stats,
                       (const float*)nullptr, (const float*)nullptr,
                       TOK, OUTC, 128, 4, 0);
    hipLaunchKernelGGL(gemm_bf16_kernel, dim3(OUTC / 128, TOK / 128), dim3(256), 0, stream,
                       dcbuf, wpw, pw_b,
                       (bf16*)nullptr, out, stats,
                       bn_g, bn_b,
                       TOK, OUTC, 128, 5, 0);
}